// Round 9
// baseline (1299.991 us; speedup 1.0000x reference)
//
#include <hip/hip_runtime.h>
#include <cstddef>
#include <cstdint>

#define DIM 2560
#define NH 40
#define HDD 64
#define SD 64
#define KC 4
#define BB 2
#define LL 2048
#define MTOT (BB*LL)      // 4096
#define NPROJ (NH*3*SD)   // 7680
#define NC 16             // scan chunks
#define CH (LL/NC)        // 128 steps per chunk
#define BH (BB*NH)        // 80

typedef unsigned short u16;
typedef __attribute__((ext_vector_type(8))) short bf16x8;
typedef __attribute__((ext_vector_type(4))) float f32x4;

__device__ inline float bf2f(u16 u) { return __uint_as_float(((unsigned)u) << 16); }
__device__ inline float bflo(unsigned u) { return __uint_as_float(u << 16); }
__device__ inline float bfhi(unsigned u) { return __uint_as_float(u & 0xffff0000u); }
__device__ inline u16 f2bf(float f) {
  unsigned x = __float_as_uint(f);
  unsigned r = (x + 0x7fffu + ((x >> 16) & 1u)) >> 16;   // RNE
  return (u16)r;
}

__device__ inline void gload16(const void* g, void* lds) {
  __builtin_amdgcn_global_load_lds(
      (const __attribute__((address_space(1))) void*)g,
      (__attribute__((address_space(3))) void*)(uint32_t)(size_t)lds,
      16, 0, 0);
}

// ---------------------------------------------------------------
__global__ __launch_bounds__(256) void cvt_kernel(
    const float* __restrict__ src, u16* __restrict__ dst, int n4) {
  int i = blockIdx.x * 256 + threadIdx.x;
  int stride = gridDim.x * 256;
  for (; i < n4; i += stride) {
    float4 v = *(const float4*)(src + (size_t)i * 4);
    ushort4 o;
    o.x = f2bf(v.x); o.y = f2bf(v.y); o.z = f2bf(v.z); o.w = f2bf(v.w);
    *(ushort4*)(dst + (size_t)i * 4) = o;
  }
}

// ---------------------------------------------------------------
__global__ __launch_bounds__(256) void fill_kernel(float* p, int n, float v) {
  int i = blockIdx.x * 256 + threadIdx.x;
  if (i < n) p[i] = v;
}

// ---------------------------------------------------------------
__device__ inline void block_reduce2(float& sum, float& sq, float* red) {
  #pragma unroll
  for (int off = 32; off; off >>= 1) {
    sum += __shfl_down(sum, off, 64);
    sq  += __shfl_down(sq,  off, 64);
  }
  int wid = threadIdx.x >> 6, lane = threadIdx.x & 63;
  if (lane == 0) { red[wid*2] = sum; red[wid*2+1] = sq; }
  __syncthreads();
  sum = red[0] + red[2] + red[4] + red[6];
  sq  = red[1] + red[3] + red[5] + red[7];
}

// ---------------------------------------------------------------
// conv (causal depthwise, K=4) + residual + LayerNorm1 -> bf16
// ---------------------------------------------------------------
__global__ __launch_bounds__(256) void conv_ln1_kernel(
    const float* __restrict__ x, const float* __restrict__ cw,
    const float* __restrict__ g1, const float* __restrict__ b1,
    u16* __restrict__ x1) {
  __shared__ float red[8];
  int bl = blockIdx.x;
  int l  = bl & (LL - 1);
  int t  = threadIdx.x;
  const float* xr = x + (size_t)bl * DIM;
  float vals[10];
  float sum = 0.f, sq = 0.f;
  #pragma unroll
  for (int i = 0; i < 10; ++i) {
    int d = t + 256 * i;
    float acc = xr[d];
    #pragma unroll
    for (int j = 0; j < KC; ++j) {
      int ll = l - (KC - 1) + j;
      if (ll >= 0) acc += x[(size_t)(bl - l + ll) * DIM + d] * cw[d * KC + j];
    }
    vals[i] = acc; sum += acc; sq += acc * acc;
  }
  block_reduce2(sum, sq, red);
  float mean = sum * (1.f / DIM);
  float var  = sq * (1.f / DIM) - mean * mean;
  float rstd = rsqrtf(var + 1e-5f);
  u16* orow = x1 + (size_t)bl * DIM;
  #pragma unroll
  for (int i = 0; i < 10; ++i) {
    int d = t + 256 * i;
    orow[d] = f2bf((vals[i] - mean) * rstd * g1[d] + b1[d]);
  }
}

// ---------------------------------------------------------------
// LN2: out = LN(x1 + y2), bf16 inputs -> fp32 out
// ---------------------------------------------------------------
__global__ __launch_bounds__(256) void ln2_kernel(
    const u16* __restrict__ x1, const u16* __restrict__ y2,
    const float* __restrict__ g2, const float* __restrict__ b2,
    float* __restrict__ out) {
  __shared__ float red[8];
  int bl = blockIdx.x;
  int t  = threadIdx.x;
  const u16* ar = x1 + (size_t)bl * DIM;
  const u16* br = y2 + (size_t)bl * DIM;
  float vals[10];
  float sum = 0.f, sq = 0.f;
  #pragma unroll
  for (int i = 0; i < 10; ++i) {
    int d = t + 256 * i;
    float v = bf2f(ar[d]) + bf2f(br[d]);
    vals[i] = v; sum += v; sq += v * v;
  }
  block_reduce2(sum, sq, red);
  float mean = sum * (1.f / DIM);
  float var  = sq * (1.f / DIM) - mean * mean;
  float rstd = rsqrtf(var + 1e-5f);
  float* orow = out + (size_t)bl * DIM;
  #pragma unroll
  for (int i = 0; i < 10; ++i) {
    int d = t + 256 * i;
    orow[d] = (vals[i] - mean) * rstd * g2[d] + b2[d];
  }
}

// ---------------------------------------------------------------
// MFMA bf16 GEMM (round-7 core: BK=32, no swizzle).
// EPI: 0 plain | 1 sigmoid | 2 decay sigmoid(-(v+bias))
// ---------------------------------------------------------------
template<int EPI, bool REMAP>
__global__ __launch_bounds__(256) void gemm_mfma(
    const u16* __restrict__ A, int lda,
    const u16* __restrict__ Wb,
    const float* __restrict__ bias,
    u16* __restrict__ C1, int ldc,
    int K) {
  __shared__ u16 As[128 * 32];
  __shared__ u16 Bs[128 * 32];
  int t = threadIdx.x;
  int w = t >> 6, l = t & 63;
  int wr = w >> 1, wc = w & 1;
  int m0 = blockIdx.y * 128;
  int n0 = blockIdx.x * 128;

  f32x4 acc[4][4];
  #pragma unroll
  for (int i = 0; i < 4; ++i)
    #pragma unroll
    for (int j = 0; j < 4; ++j)
      acc[i][j] = (f32x4){0.f, 0.f, 0.f, 0.f};

  int srow = 32 * w + (l >> 2);
  int scol = (l & 3) * 8;
  const u16* gA = A  + (size_t)(m0 + srow) * lda + scol;
  const u16* gB = Wb + (size_t)(n0 + srow) * K   + scol;
  u16* ldsA = As + (32 * w) * 32;
  u16* ldsB = Bs + (32 * w) * 32;

  int fr = l & 15;
  int kc = (l >> 4) * 8;
  const u16* rA = As + (size_t)(wr * 64 + fr) * 32 + kc;
  const u16* rB = Bs + (size_t)(wc * 64 + fr) * 32 + kc;

  for (int k0 = 0; k0 < K; k0 += 32) {
    gload16(gA + k0, ldsA);
    gload16(gA + (size_t)16 * lda + k0, ldsA + 16 * 32);
    gload16(gB + k0, ldsB);
    gload16(gB + (size_t)16 * K + k0, ldsB + 16 * 32);
    __syncthreads();
    bf16x8 a[4], b[4];
    #pragma unroll
    for (int i = 0; i < 4; ++i) a[i] = *(const bf16x8*)(rA + i * 16 * 32);
    #pragma unroll
    for (int j = 0; j < 4; ++j) b[j] = *(const bf16x8*)(rB + j * 16 * 32);
    #pragma unroll
    for (int i = 0; i < 4; ++i)
      #pragma unroll
      for (int j = 0; j < 4; ++j)
        acc[i][j] = __builtin_amdgcn_mfma_f32_16x16x32_bf16(a[i], b[j], acc[i][j], 0, 0, 0);
    __syncthreads();
  }

  int crow = (l >> 4) * 4;
  int ccol = l & 15;
  #pragma unroll
  for (int j = 0; j < 4; ++j) {
    int col = n0 + wc * 64 + j * 16 + ccol;
    int colr = col;
    if (REMAP) {
      int h = col / 192, r3 = col % 192;
      colr = (r3 / 64) * 2560 + h * 64 + (r3 & 63);
    }
    float bv = (EPI == 2) ? bias[col] : 0.f;
    #pragma unroll
    for (int i = 0; i < 4; ++i) {
      #pragma unroll
      for (int q = 0; q < 4; ++q) {
        int row = m0 + wr * 64 + i * 16 + crow + q;
        float v = acc[i][j][q];
        if constexpr (EPI == 1) v = 1.f / (1.f + expf(-v));
        if constexpr (EPI == 2) v = 1.f / (1.f + expf(v + bv));
        C1[(size_t)row * ldc + colr] = f2bf(v);
      }
    }
  }
}

// ---------------------------------------------------------------
// Dual-output MFMA GEMM: A staged once, two B operands.
// MODE 3: C1 = sigmoid(A@W1^T), C2 = sigmoid(A@W2^T)   (r, g)
// MODE 4: C1 = (A@W1^T) * (A@W2^T)                     (kv)
// BK=32; LDS 24 KB; 32 MFMA per K-step (2x MFMA:stage ratio).
// ---------------------------------------------------------------
template<int MODE>
__global__ __launch_bounds__(256) void gemm_dual(
    const u16* __restrict__ A, int lda,
    const u16* __restrict__ W1, const u16* __restrict__ W2,
    u16* __restrict__ C1, u16* __restrict__ C2,
    int ldc, int K) {
  __shared__ u16 As[128 * 32];
  __shared__ u16 B1s[128 * 32];
  __shared__ u16 B2s[128 * 32];
  int t = threadIdx.x;
  int w = t >> 6, l = t & 63;
  int wr = w >> 1, wc = w & 1;
  int m0 = blockIdx.y * 128;
  int n0 = blockIdx.x * 128;

  f32x4 acc1[4][4], acc2[4][4];
  #pragma unroll
  for (int i = 0; i < 4; ++i)
    #pragma unroll
    for (int j = 0; j < 4; ++j) {
      acc1[i][j] = (f32x4){0.f, 0.f, 0.f, 0.f};
      acc2[i][j] = (f32x4){0.f, 0.f, 0.f, 0.f};
    }

  int srow = 32 * w + (l >> 2);
  int scol = (l & 3) * 8;
  const u16* gA  = A  + (size_t)(m0 + srow) * lda + scol;
  const u16* gB1 = W1 + (size_t)(n0 + srow) * K   + scol;
  const u16* gB2 = W2 + (size_t)(n0 + srow) * K   + scol;
  u16* ldsA  = As  + (32 * w) * 32;
  u16* ldsB1 = B1s + (32 * w) * 32;
  u16* ldsB2 = B2s + (32 * w) * 32;

  int fr = l & 15;
  int kc = (l >> 4) * 8;
  const u16* rA  = As  + (size_t)(wr * 64 + fr) * 32 + kc;
  const u16* rB1 = B1s + (size_t)(wc * 64 + fr) * 32 + kc;
  const u16* rB2 = B2s + (size_t)(wc * 64 + fr) * 32 + kc;

  for (int k0 = 0; k0 < K; k0 += 32) {
    gload16(gA + k0, ldsA);
    gload16(gA + (size_t)16 * lda + k0, ldsA + 16 * 32);
    gload16(gB1 + k0, ldsB1);
    gload16(gB1 + (size_t)16 * K + k0, ldsB1 + 16 * 32);
    gload16(gB2 + k0, ldsB2);
    gload16(gB2 + (size_t)16 * K + k0, ldsB2 + 16 * 32);
    __syncthreads();
    bf16x8 a[4], b1[4], b2[4];
    #pragma unroll
    for (int i = 0; i < 4; ++i) {
      a[i]  = *(const bf16x8*)(rA  + i * 16 * 32);
      b1[i] = *(const bf16x8*)(rB1 + i * 16 * 32);
      b2[i] = *(const bf16x8*)(rB2 + i * 16 * 32);
    }
    #pragma unroll
    for (int i = 0; i < 4; ++i)
      #pragma unroll
      for (int j = 0; j < 4; ++j) {
        acc1[i][j] = __builtin_amdgcn_mfma_f32_16x16x32_bf16(a[i], b1[j], acc1[i][j], 0, 0, 0);
        acc2[i][j] = __builtin_amdgcn_mfma_f32_16x16x32_bf16(a[i], b2[j], acc2[i][j], 0, 0, 0);
      }
    __syncthreads();
  }

  int crow = (l >> 4) * 4;
  int ccol = l & 15;
  #pragma unroll
  for (int j = 0; j < 4; ++j) {
    int col = n0 + wc * 64 + j * 16 + ccol;
    #pragma unroll
    for (int i = 0; i < 4; ++i) {
      #pragma unroll
      for (int q = 0; q < 4; ++q) {
        int row = m0 + wr * 64 + i * 16 + crow + q;
        size_t idx = (size_t)row * ldc + col;
        float v1 = acc1[i][j][q];
        float v2 = acc2[i][j][q];
        if constexpr (MODE == 3) {
          C1[idx] = f2bf(1.f / (1.f + expf(-v1)));
          C2[idx] = f2bf(1.f / (1.f + expf(-v2)));
        } else {
          C1[idx] = f2bf(v1 * v2);
        }
      }
    }
  }
}

// ===============================================================
// Chunked parallel scan (round-7 structure; phase 3 fuses r*g gate).
// ===============================================================
__global__ __launch_bounds__(128) void scan_local_kernel(
    const u16* __restrict__ wdec, const u16* __restrict__ proj,
    const u16* __restrict__ kvb, u16* __restrict__ yout,
    float* __restrict__ Sbuf, float* __restrict__ Pbuf) {
  int bx = blockIdx.x;
  int bh = bx / NC, c = bx % NC;
  int b = bh / NH, h = bh % NH;
  int wv = threadIdx.x >> 6;
  int lane = threadIdx.x & 63;
  int sg = lane >> 3, dd = lane & 7;
  int s0 = sg * 8;
  int d0 = wv * 32 + dd * 4;
  int l0 = c * CH;

  const u16* fw = wdec + ((size_t)(b * LL + l0)) * DIM + h * 64 + s0;
  const u16* fB = proj + ((size_t)(b * LL + l0)) * NPROJ + 2560 + h * 64 + s0;
  const u16* fC = fB + 2560;
  const u16* fk = kvb + ((size_t)(b * LL + l0)) * DIM + h * 64 + d0;
  u16* py = yout + ((size_t)(b * LL + l0)) * NPROJ + h * 64 + d0;

  float st[8][4];
  float pc[8];
  #pragma unroll
  for (int i = 0; i < 8; ++i) {
    pc[i] = 1.f;
    #pragma unroll
    for (int j = 0; j < 4; ++j) st[i][j] = 0.f;
  }

#define P1_DECL(n) uint4 wS##n, BS##n, CS##n; uint2 kS##n
#define P1_LOAD(n) do { \
    wS##n = *(const uint4*)fw; BS##n = *(const uint4*)fB; \
    CS##n = *(const uint4*)fC; kS##n = *(const uint2*)fk; \
    fw += DIM; fB += NPROJ; fC += NPROJ; fk += DIM; } while (0)
#define P1_PROC(n) do { \
    float wv8[8], Bv[8], Cv[8], kv4[4], pr[4]; \
    wv8[0]=bflo(wS##n.x); wv8[1]=bfhi(wS##n.x); wv8[2]=bflo(wS##n.y); wv8[3]=bfhi(wS##n.y); \
    wv8[4]=bflo(wS##n.z); wv8[5]=bfhi(wS##n.z); wv8[6]=bflo(wS##n.w); wv8[7]=bfhi(wS##n.w); \
    Bv[0]=bflo(BS##n.x); Bv[1]=bfhi(BS##n.x); Bv[2]=bflo(BS##n.y); Bv[3]=bfhi(BS##n.y); \
    Bv[4]=bflo(BS##n.z); Bv[5]=bfhi(BS##n.z); Bv[6]=bflo(BS##n.w); Bv[7]=bfhi(BS##n.w); \
    Cv[0]=bflo(CS##n.x); Cv[1]=bfhi(CS##n.x); Cv[2]=bflo(CS##n.y); Cv[3]=bfhi(CS##n.y); \
    Cv[4]=bflo(CS##n.z); Cv[5]=bfhi(CS##n.z); Cv[6]=bflo(CS##n.w); Cv[7]=bfhi(CS##n.w); \
    kv4[0]=bflo(kS##n.x); kv4[1]=bfhi(kS##n.x); kv4[2]=bflo(kS##n.y); kv4[3]=bfhi(kS##n.y); \
    pr[0]=0.f; pr[1]=0.f; pr[2]=0.f; pr[3]=0.f; \
    _Pragma("unroll") \
    for (int i = 0; i < 8; ++i) { \
      pc[i] *= wv8[i]; \
      _Pragma("unroll") \
      for (int j = 0; j < 4; ++j) { \
        st[i][j] = fmaf(wv8[i], st[i][j], Bv[i] * kv4[j]); \
        pr[j] = fmaf(st[i][j], Cv[i], pr[j]); } } \
    _Pragma("unroll") \
    for (int j = 0; j < 4; ++j) { \
      pr[j] += __shfl_xor(pr[j], 8, 64); \
      pr[j] += __shfl_xor(pr[j], 16, 64); \
      pr[j] += __shfl_xor(pr[j], 32, 64); } \
    if (lane < 8) { \
      uint2 ov; \
      ov.x = (unsigned)f2bf(pr[0]) | ((unsigned)f2bf(pr[1]) << 16); \
      ov.y = (unsigned)f2bf(pr[2]) | ((unsigned)f2bf(pr[3]) << 16); \
      *(uint2*)py = ov; } \
    py += NPROJ; } while (0)

  P1_DECL(0); P1_DECL(1); P1_DECL(2); P1_DECL(3);
  P1_LOAD(0); P1_LOAD(1); P1_LOAD(2); P1_LOAD(3);
  for (int l = 0; l < CH; l += 4) {
    P1_PROC(0); P1_LOAD(0);
    P1_PROC(1); P1_LOAD(1);
    P1_PROC(2); P1_LOAD(2);
    P1_PROC(3); P1_LOAD(3);
  }
#undef P1_DECL
#undef P1_LOAD
#undef P1_PROC

  float* Sp = Sbuf + (((size_t)c * BH + bh) * 64 + s0) * 64 + d0;
  #pragma unroll
  for (int i = 0; i < 8; ++i) {
    float4 v; v.x = st[i][0]; v.y = st[i][1]; v.z = st[i][2]; v.w = st[i][3];
    *(float4*)(Sp + (size_t)i * 64) = v;
  }
  if (wv == 0 && dd == 0) {
    #pragma unroll
    for (int i = 0; i < 8; ++i)
      Pbuf[((size_t)c * BH + bh) * 64 + s0 + i] = pc[i];
  }
}

// ---------------------------------------------------------------
__global__ __launch_bounds__(256) void scan_combine_kernel(
    float* __restrict__ Sbuf, const float* __restrict__ Pbuf,
    float* __restrict__ fstate) {
  int bh = blockIdx.x;
  int t = threadIdx.x;
  int s = t >> 2, j0 = (t & 3) * 16;
  float stin[16];
  #pragma unroll
  for (int k = 0; k < 16; ++k) stin[k] = 0.f;
  for (int c = 0; c < NC; ++c) {
    float* Sp = Sbuf + (((size_t)c * BH + bh) * 64 + s) * 64 + j0;
    float Pc = Pbuf[((size_t)c * BH + bh) * 64 + s];
    #pragma unroll
    for (int q = 0; q < 4; ++q) {
      float4 a = *(const float4*)(Sp + q * 4);
      float4 cur;
      cur.x = stin[q*4+0]; cur.y = stin[q*4+1];
      cur.z = stin[q*4+2]; cur.w = stin[q*4+3];
      *(float4*)(Sp + q * 4) = cur;           // S slot now holds st_in for chunk c
      stin[q*4+0] = a.x + Pc * stin[q*4+0];
      stin[q*4+1] = a.y + Pc * stin[q*4+1];
      stin[q*4+2] = a.z + Pc * stin[q*4+2];
      stin[q*4+3] = a.w + Pc * stin[q*4+3];
    }
  }
  float* fp = fstate + ((size_t)bh * 64 + s) * 64 + j0;
  #pragma unroll
  for (int q = 0; q < 4; ++q) {
    float4 v;
    v.x = stin[q*4+0]; v.y = stin[q*4+1];
    v.z = stin[q*4+2]; v.w = stin[q*4+3];
    *(float4*)(fp + q * 4) = v;
  }
}

// ---------------------------------------------------------------
// Phase 3 + fused gate: y_final = r * (y_local + C.(cumw*st_in)) * g
// ---------------------------------------------------------------
__global__ __launch_bounds__(128) void scan_correct_kernel(
    const u16* __restrict__ wdec, const u16* __restrict__ proj,
    const u16* __restrict__ rb, const u16* __restrict__ gb,
    const float* __restrict__ Sbuf, u16* __restrict__ yio) {
  int bx = blockIdx.x;
  int bh = bx / NC, c = bx % NC;
  int b = bh / NH, h = bh % NH;
  int wv = threadIdx.x >> 6;
  int lane = threadIdx.x & 63;
  int sg = lane >> 3, dd = lane & 7;
  int s0 = sg * 8;
  int d0 = wv * 32 + dd * 4;
  int l0 = c * CH;

  const float* Sp = Sbuf + (((size_t)c * BH + bh) * 64 + s0) * 64 + d0;
  float stin[8][4];
  #pragma unroll
  for (int i = 0; i < 8; ++i) {
    float4 v = *(const float4*)(Sp + (size_t)i * 64);
    stin[i][0] = v.x; stin[i][1] = v.y; stin[i][2] = v.z; stin[i][3] = v.w;
  }

  const u16* fw = wdec + ((size_t)(b * LL + l0)) * DIM + h * 64 + s0;
  const u16* fC = proj + ((size_t)(b * LL + l0)) * NPROJ + 5120 + h * 64 + s0;
  const u16* fy = yio  + ((size_t)(b * LL + l0)) * NPROJ + h * 64 + d0;
  const u16* fr2 = rb + ((size_t)(b * LL + l0)) * DIM + h * 64 + d0;
  const u16* fg2 = gb + ((size_t)(b * LL + l0)) * DIM + h * 64 + d0;
  u16* py = yio + ((size_t)(b * LL + l0)) * NPROJ + h * 64 + d0;

  float pc[8];
  #pragma unroll
  for (int i = 0; i < 8; ++i) pc[i] = 1.f;

#define P3_DECL(n) uint4 wT##n, CT##n; uint2 yT##n, rT##n, gT##n
#define P3_LOAD(n) do { \
    wT##n = *(const uint4*)fw; CT##n = *(const uint4*)fC; \
    yT##n = *(const uint2*)fy; rT##n = *(const uint2*)fr2; gT##n = *(const uint2*)fg2; \
    fw += DIM; fC += NPROJ; fy += NPROJ; fr2 += DIM; fg2 += DIM; } while (0)
#define P3_PROC(n) do { \
    float wv8[8], Cv[8], ac[8], pr[4]; \
    wv8[0]=bflo(wT##n.x); wv8[1]=bfhi(wT##n.x); wv8[2]=bflo(wT##n.y); wv8[3]=bfhi(wT##n.y); \
    wv8[4]=bflo(wT##n.z); wv8[5]=bfhi(wT##n.z); wv8[6]=bflo(wT##n.w); wv8[7]=bfhi(wT##n.w); \
    Cv[0]=bflo(CT##n.x); Cv[1]=bfhi(CT##n.x); Cv[2]=bflo(CT##n.y); Cv[3]=bfhi(CT##n.y); \
    Cv[4]=bflo(CT##n.z); Cv[5]=bfhi(CT##n.z); Cv[6]=bflo(CT##n.w); Cv[7]=bfhi(CT##n.w); \
    pr[0]=0.f; pr[1]=0.f; pr[2]=0.f; pr[3]=0.f; \
    _Pragma("unroll") \
    for (int i = 0; i < 8; ++i) { \
      pc[i] *= wv8[i]; ac[i] = pc[i] * Cv[i]; \
      _Pragma("unroll") \
      for (int j = 0; j < 4; ++j) pr[j] = fmaf(ac[i], stin[i][j], pr[j]); } \
    _Pragma("unroll") \
    for (int j = 0; j < 4; ++j) { \
      pr[j] += __shfl_xor(pr[j], 8, 64); \
      pr[j] += __shfl_xor(pr[j], 16, 64); \
      pr[j] += __shfl_xor(pr[j], 32, 64); } \
    if (lane < 8) { \
      float y0 = (bflo(yT##n.x) + pr[0]) * bflo(rT##n.x) * bflo(gT##n.x); \
      float y1 = (bfhi(yT##n.x) + pr[1]) * bfhi(rT##n.x) * bfhi(gT##n.x); \
      float y2 = (bflo(yT##n.y) + pr[2]) * bflo(rT##n.y) * bflo(gT##n.y); \
      float y3 = (bfhi(yT##n.y) + pr[3]) * bfhi(rT##n.y) * bfhi(gT##n.y); \
      uint2 ov; \
      ov.x = (unsigned)f2bf(y0) | ((unsigned)f2bf(y1) << 16); \
      ov.y = (unsigned)f2bf(y2) | ((unsigned)f2bf(y3) << 16); \
      *(uint2*)py = ov; } \
    py += NPROJ; } while (0)

  P3_DECL(0); P3_DECL(1); P3_DECL(2); P3_DECL(3);
  P3_LOAD(0); P3_LOAD(1); P3_LOAD(2); P3_LOAD(3);
  for (int l = 0; l < CH; l += 4) {
    P3_PROC(0); P3_LOAD(0);
    P3_PROC(1); P3_LOAD(1);
    P3_PROC(2); P3_LOAD(2);
    P3_PROC(3); P3_LOAD(3);
  }
#undef P3_DECL
#undef P3_LOAD
#undef P3_PROC
}

// ---------------------------------------------------------------
extern "C" void kernel_launch(void* const* d_in, const int* in_sizes, int n_in,
                              void* d_out, int out_size, void* d_ws, size_t ws_size,
                              hipStream_t stream) {
  const float* x    = (const float*)d_in[0];
  const float* W_r  = (const float*)d_in[1];
  const float* W_k  = (const float*)d_in[2];
  const float* W_v  = (const float*)d_in[3];
  const float* W_g  = (const float*)d_in[4];
  const float* W_xp = (const float*)d_in[5];
  const float* W_dt = (const float*)d_in[6];
  const float* b_dt = (const float*)d_in[7];
  const float* cw   = (const float*)d_in[8];
  const float* ln1g = (const float*)d_in[9];
  const float* ln1b = (const float*)d_in[10];
  const float* ln2g = (const float*)d_in[11];
  const float* ln2b = (const float*)d_in[12];
  const float* W_o  = (const float*)d_in[13];

  float* out    = (float*)d_out;
  float* fstate = out + (size_t)MTOT * DIM;

  const size_t nBL = (size_t)MTOT * DIM;
  const size_t nPJ = (size_t)MTOT * NPROJ;
  const size_t nWX = (size_t)NPROJ * DIM;
  const size_t nDD = (size_t)DIM * DIM;
  const size_t needed = (nBL * 5 + nPJ + nWX) * sizeof(u16);  // ~207 MB
  if (ws_size < needed) {
    fill_kernel<<<(out_size + 255) / 256, 256, 0, stream>>>(out, out_size, 1234.5f);
    return;
  }

  u16* wsp  = (u16*)d_ws;
  u16* x1   = wsp;
  u16* proj = x1 + nBL;
  u16* wdec = proj + nPJ;       // reused for y2 after recurrence
  u16* rb   = wdec + nBL;
  u16* gb   = rb + nBL;
  u16* kvb  = gb + nBL;
  u16* wscr = kvb + nBL;        // weight scratch (nWX elems); scan S/P live here
  u16* wscr2 = wscr + nDD;      // second weight slot for dual GEMMs
  float* Sbuf = (float*)wscr;                       // NC*BH*64*64 fp32 = 21 MB
  float* Pbuf = Sbuf + (size_t)NC * BH * 64 * 64;   // NC*BH*64 fp32 = 0.3 MB

  const int nDD4 = (int)(nDD / 4);

  // 1. conv + LN1 -> x1 (bf16)
  conv_ln1_kernel<<<MTOT, 256, 0, stream>>>(x, cw, ln1g, ln1b, x1);

  // 2. proj = x1 @ W_xproj^T  (REMAP columns to [dt|B|C])
  cvt_kernel<<<2048, 256, 0, stream>>>(W_xp, wscr, NPROJ * DIM / 4);
  gemm_mfma<0,true ><<<dim3(NPROJ/128, MTOT/128), 256, 0, stream>>>(x1, DIM, wscr, nullptr, proj, NPROJ, DIM);

  // 3. w = exp(-softplus(proj_dt @ W_dt^T + b_dt))
  cvt_kernel<<<2048, 256, 0, stream>>>(W_dt, wscr, nDD4);
  gemm_mfma<2,false><<<dim3(DIM/128, MTOT/128), 256, 0, stream>>>(proj, NPROJ, wscr, b_dt, wdec, DIM, DIM);

  // 4. r,g dual: r = sigmoid(x1@W_r^T), g = sigmoid(x1@W_g^T)
  cvt_kernel<<<2048, 256, 0, stream>>>(W_r, wscr, nDD4);
  cvt_kernel<<<2048, 256, 0, stream>>>(W_g, wscr2, nDD4);
  gemm_dual<3><<<dim3(DIM/128, MTOT/128), 256, 0, stream>>>(x1, DIM, wscr, wscr2, rb, gb, DIM, DIM);

  // 5. kv dual: kv = (x1@W_k^T) * (x1@W_v^T)
  cvt_kernel<<<2048, 256, 0, stream>>>(W_k, wscr, nDD4);
  cvt_kernel<<<2048, 256, 0, stream>>>(W_v, wscr2, nDD4);
  gemm_dual<4><<<dim3(DIM/128, MTOT/128), 256, 0, stream>>>(x1, DIM, wscr, wscr2, kvb, nullptr, DIM, DIM);

  // 6. chunked scan: local -> combine(fstate) -> correct(+gate fused)
  scan_local_kernel<<<BH * NC, 128, 0, stream>>>(wdec, proj, kvb, proj, Sbuf, Pbuf);
  scan_combine_kernel<<<BH, 256, 0, stream>>>(Sbuf, Pbuf, fstate);
  scan_correct_kernel<<<BH * NC, 128, 0, stream>>>(wdec, proj, rb, gb, Sbuf, proj);

  // 7. y2 = out_inner @ W_out^T -> wdec (reuse); A = proj y-region (lda=NPROJ)
  cvt_kernel<<<2048, 256, 0, stream>>>(W_o, wscr, nDD4);
  gemm_mfma<0,false><<<dim3(DIM/128, MTOT/128), 256, 0, stream>>>(proj, NPROJ, wscr, nullptr, wdec, DIM, DIM);

  // 8. out = LN(x1 + y2) -> fp32
  ln2_kernel<<<MTOT, 256, 0, stream>>>(x1, wdec, ln2g, ln2b, out);
}

// Round 10
// 1053.143 us; speedup vs baseline: 1.2344x; 1.2344x over previous
//
#include <hip/hip_runtime.h>
#include <cstddef>
#include <cstdint>

#define DIM 2560
#define NH 40
#define HDD 64
#define SD 64
#define KC 4
#define BB 2
#define LL 2048
#define MTOT (BB*LL)      // 4096
#define NPROJ (NH*3*SD)   // 7680
#define NC 16             // scan chunks
#define CH (LL/NC)        // 128 steps per chunk
#define BH (BB*NH)        // 80

typedef unsigned short u16;
typedef __attribute__((ext_vector_type(8))) short bf16x8;
typedef __attribute__((ext_vector_type(4))) float f32x4;

__device__ inline float bf2f(u16 u) { return __uint_as_float(((unsigned)u) << 16); }
__device__ inline float bflo(unsigned u) { return __uint_as_float(u << 16); }
__device__ inline float bfhi(unsigned u) { return __uint_as_float(u & 0xffff0000u); }
__device__ inline u16 f2bf(float f) {
  unsigned x = __float_as_uint(f);
  unsigned r = (x + 0x7fffu + ((x >> 16) & 1u)) >> 16;   // RNE
  return (u16)r;
}

__device__ inline void gload16(const void* g, void* lds) {
  __builtin_amdgcn_global_load_lds(
      (const __attribute__((address_space(1))) void*)g,
      (__attribute__((address_space(3))) void*)(uint32_t)(size_t)lds,
      16, 0, 0);
}

// ---------------------------------------------------------------
__global__ __launch_bounds__(256) void cvt_kernel(
    const float* __restrict__ src, u16* __restrict__ dst, int n4) {
  int i = blockIdx.x * 256 + threadIdx.x;
  int stride = gridDim.x * 256;
  for (; i < n4; i += stride) {
    float4 v = *(const float4*)(src + (size_t)i * 4);
    ushort4 o;
    o.x = f2bf(v.x); o.y = f2bf(v.y); o.z = f2bf(v.z); o.w = f2bf(v.w);
    *(ushort4*)(dst + (size_t)i * 4) = o;
  }
}

// ---------------------------------------------------------------
__global__ __launch_bounds__(256) void fill_kernel(float* p, int n, float v) {
  int i = blockIdx.x * 256 + threadIdx.x;
  if (i < n) p[i] = v;
}

// ---------------------------------------------------------------
__device__ inline void block_reduce2(float& sum, float& sq, float* red) {
  #pragma unroll
  for (int off = 32; off; off >>= 1) {
    sum += __shfl_down(sum, off, 64);
    sq  += __shfl_down(sq,  off, 64);
  }
  int wid = threadIdx.x >> 6, lane = threadIdx.x & 63;
  if (lane == 0) { red[wid*2] = sum; red[wid*2+1] = sq; }
  __syncthreads();
  sum = red[0] + red[2] + red[4] + red[6];
  sq  = red[1] + red[3] + red[5] + red[7];
}

// ---------------------------------------------------------------
// conv (causal depthwise, K=4) + residual + LayerNorm1 -> bf16
// ---------------------------------------------------------------
__global__ __launch_bounds__(256) void conv_ln1_kernel(
    const float* __restrict__ x, const float* __restrict__ cw,
    const float* __restrict__ g1, const float* __restrict__ b1,
    u16* __restrict__ x1) {
  __shared__ float red[8];
  int bl = blockIdx.x;
  int l  = bl & (LL - 1);
  int t  = threadIdx.x;
  const float* xr = x + (size_t)bl * DIM;
  float vals[10];
  float sum = 0.f, sq = 0.f;
  #pragma unroll
  for (int i = 0; i < 10; ++i) {
    int d = t + 256 * i;
    float acc = xr[d];
    #pragma unroll
    for (int j = 0; j < KC; ++j) {
      int ll = l - (KC - 1) + j;
      if (ll >= 0) acc += x[(size_t)(bl - l + ll) * DIM + d] * cw[d * KC + j];
    }
    vals[i] = acc; sum += acc; sq += acc * acc;
  }
  block_reduce2(sum, sq, red);
  float mean = sum * (1.f / DIM);
  float var  = sq * (1.f / DIM) - mean * mean;
  float rstd = rsqrtf(var + 1e-5f);
  u16* orow = x1 + (size_t)bl * DIM;
  #pragma unroll
  for (int i = 0; i < 10; ++i) {
    int d = t + 256 * i;
    orow[d] = f2bf((vals[i] - mean) * rstd * g1[d] + b1[d]);
  }
}

// ---------------------------------------------------------------
// LN2: out = LN(x1 + y2), bf16 inputs -> fp32 out
// ---------------------------------------------------------------
__global__ __launch_bounds__(256) void ln2_kernel(
    const u16* __restrict__ x1, const u16* __restrict__ y2,
    const float* __restrict__ g2, const float* __restrict__ b2,
    float* __restrict__ out) {
  __shared__ float red[8];
  int bl = blockIdx.x;
  int t  = threadIdx.x;
  const u16* ar = x1 + (size_t)bl * DIM;
  const u16* br = y2 + (size_t)bl * DIM;
  float vals[10];
  float sum = 0.f, sq = 0.f;
  #pragma unroll
  for (int i = 0; i < 10; ++i) {
    int d = t + 256 * i;
    float v = bf2f(ar[d]) + bf2f(br[d]);
    vals[i] = v; sum += v; sq += v * v;
  }
  block_reduce2(sum, sq, red);
  float mean = sum * (1.f / DIM);
  float var  = sq * (1.f / DIM) - mean * mean;
  float rstd = rsqrtf(var + 1e-5f);
  float* orow = out + (size_t)bl * DIM;
  #pragma unroll
  for (int i = 0; i < 10; ++i) {
    int d = t + 256 * i;
    orow[d] = (vals[i] - mean) * rstd * g2[d] + b2[d];
  }
}

// ---------------------------------------------------------------
// MFMA bf16 GEMM (round-7 core: BK=32, no swizzle).
// EPI: 0 plain | 2 decay sigmoid(-(v+bias))
// ---------------------------------------------------------------
template<int EPI, bool REMAP>
__global__ __launch_bounds__(256) void gemm_mfma(
    const u16* __restrict__ A, int lda,
    const u16* __restrict__ Wb,
    const float* __restrict__ bias,
    u16* __restrict__ C1, int ldc,
    int K) {
  __shared__ u16 As[128 * 32];
  __shared__ u16 Bs[128 * 32];
  int t = threadIdx.x;
  int w = t >> 6, l = t & 63;
  int wr = w >> 1, wc = w & 1;
  int m0 = blockIdx.y * 128;
  int n0 = blockIdx.x * 128;

  f32x4 acc[4][4];
  #pragma unroll
  for (int i = 0; i < 4; ++i)
    #pragma unroll
    for (int j = 0; j < 4; ++j)
      acc[i][j] = (f32x4){0.f, 0.f, 0.f, 0.f};

  int srow = 32 * w + (l >> 2);
  int scol = (l & 3) * 8;
  const u16* gA = A  + (size_t)(m0 + srow) * lda + scol;
  const u16* gB = Wb + (size_t)(n0 + srow) * K   + scol;
  u16* ldsA = As + (32 * w) * 32;
  u16* ldsB = Bs + (32 * w) * 32;

  int fr = l & 15;
  int kc = (l >> 4) * 8;
  const u16* rA = As + (size_t)(wr * 64 + fr) * 32 + kc;
  const u16* rB = Bs + (size_t)(wc * 64 + fr) * 32 + kc;

  for (int k0 = 0; k0 < K; k0 += 32) {
    gload16(gA + k0, ldsA);
    gload16(gA + (size_t)16 * lda + k0, ldsA + 16 * 32);
    gload16(gB + k0, ldsB);
    gload16(gB + (size_t)16 * K + k0, ldsB + 16 * 32);
    __syncthreads();
    bf16x8 a[4], b[4];
    #pragma unroll
    for (int i = 0; i < 4; ++i) a[i] = *(const bf16x8*)(rA + i * 16 * 32);
    #pragma unroll
    for (int j = 0; j < 4; ++j) b[j] = *(const bf16x8*)(rB + j * 16 * 32);
    #pragma unroll
    for (int i = 0; i < 4; ++i)
      #pragma unroll
      for (int j = 0; j < 4; ++j)
        acc[i][j] = __builtin_amdgcn_mfma_f32_16x16x32_bf16(a[i], b[j], acc[i][j], 0, 0, 0);
    __syncthreads();
  }

  int crow = (l >> 4) * 4;
  int ccol = l & 15;
  #pragma unroll
  for (int j = 0; j < 4; ++j) {
    int col = n0 + wc * 64 + j * 16 + ccol;
    int colr = col;
    if (REMAP) {
      int h = col / 192, r3 = col % 192;
      colr = (r3 / 64) * 2560 + h * 64 + (r3 & 63);
    }
    float bv = (EPI == 2) ? bias[col] : 0.f;
    #pragma unroll
    for (int i = 0; i < 4; ++i) {
      #pragma unroll
      for (int q = 0; q < 4; ++q) {
        int row = m0 + wr * 64 + i * 16 + crow + q;
        float v = acc[i][j][q];
        if constexpr (EPI == 2) v = 1.f / (1.f + expf(v + bv));
        C1[(size_t)row * ldc + colr] = f2bf(v);
      }
    }
  }
}

// ---------------------------------------------------------------
// Batched 4-way GEMM: N = 4*2560 (r|g|k|v). Same per-thread
// structure as gemm_mfma (1 acc set, 80 VGPR, occupancy intact).
// Per-block (wave-uniform) weight/output select; sigmoid for r,g.
// grid 80x32 = 2560 blocks = 10 full CU-residency rounds (no tail).
// ---------------------------------------------------------------
__global__ __launch_bounds__(256) void gemm_big4(
    const u16* __restrict__ A,
    const u16* __restrict__ W0, const u16* __restrict__ W1,
    const u16* __restrict__ W2, const u16* __restrict__ W3,
    u16* __restrict__ C0, u16* __restrict__ C1b,
    u16* __restrict__ C2, u16* __restrict__ C3,
    int K) {
  __shared__ u16 As[128 * 32];
  __shared__ u16 Bs[128 * 32];
  int t = threadIdx.x;
  int w = t >> 6, l = t & 63;
  int wr = w >> 1, wc = w & 1;
  int m0 = blockIdx.y * 128;
  int n0g = blockIdx.x * 128;           // 0..10239
  int which = n0g / 2560;
  int n0 = n0g - which * 2560;
  const u16* Wsel = (which == 0) ? W0 : (which == 1) ? W1 : (which == 2) ? W2 : W3;
  u16* Csel = (which == 0) ? C0 : (which == 1) ? C1b : (which == 2) ? C2 : C3;
  bool sig = (which < 2);

  f32x4 acc[4][4];
  #pragma unroll
  for (int i = 0; i < 4; ++i)
    #pragma unroll
    for (int j = 0; j < 4; ++j)
      acc[i][j] = (f32x4){0.f, 0.f, 0.f, 0.f};

  int srow = 32 * w + (l >> 2);
  int scol = (l & 3) * 8;
  const u16* gA = A    + (size_t)(m0 + srow) * K + scol;
  const u16* gB = Wsel + (size_t)(n0 + srow) * K + scol;
  u16* ldsA = As + (32 * w) * 32;
  u16* ldsB = Bs + (32 * w) * 32;

  int fr = l & 15;
  int kc = (l >> 4) * 8;
  const u16* rA = As + (size_t)(wr * 64 + fr) * 32 + kc;
  const u16* rB = Bs + (size_t)(wc * 64 + fr) * 32 + kc;

  for (int k0 = 0; k0 < K; k0 += 32) {
    gload16(gA + k0, ldsA);
    gload16(gA + (size_t)16 * K + k0, ldsA + 16 * 32);
    gload16(gB + k0, ldsB);
    gload16(gB + (size_t)16 * K + k0, ldsB + 16 * 32);
    __syncthreads();
    bf16x8 a[4], b[4];
    #pragma unroll
    for (int i = 0; i < 4; ++i) a[i] = *(const bf16x8*)(rA + i * 16 * 32);
    #pragma unroll
    for (int j = 0; j < 4; ++j) b[j] = *(const bf16x8*)(rB + j * 16 * 32);
    #pragma unroll
    for (int i = 0; i < 4; ++i)
      #pragma unroll
      for (int j = 0; j < 4; ++j)
        acc[i][j] = __builtin_amdgcn_mfma_f32_16x16x32_bf16(a[i], b[j], acc[i][j], 0, 0, 0);
    __syncthreads();
  }

  int crow = (l >> 4) * 4;
  int ccol = l & 15;
  #pragma unroll
  for (int j = 0; j < 4; ++j) {
    int col = n0 + wc * 64 + j * 16 + ccol;
    #pragma unroll
    for (int i = 0; i < 4; ++i) {
      #pragma unroll
      for (int q = 0; q < 4; ++q) {
        int row = m0 + wr * 64 + i * 16 + crow + q;
        float v = acc[i][j][q];
        if (sig) v = 1.f / (1.f + expf(-v));
        Csel[(size_t)row * DIM + col] = f2bf(v);
      }
    }
  }
}

// ===============================================================
// Chunked parallel scan. kv = k*v computed inline from separate
// k and v buffers (no materialized kv). Phase 3 fuses r*g gate.
// ===============================================================
__global__ __launch_bounds__(128) void scan_local_kernel(
    const u16* __restrict__ wdec, const u16* __restrict__ proj,
    const u16* __restrict__ kb, const u16* __restrict__ vb,
    u16* __restrict__ yout,
    float* __restrict__ Sbuf, float* __restrict__ Pbuf) {
  int bx = blockIdx.x;
  int bh = bx / NC, c = bx % NC;
  int b = bh / NH, h = bh % NH;
  int wv = threadIdx.x >> 6;
  int lane = threadIdx.x & 63;
  int sg = lane >> 3, dd = lane & 7;
  int s0 = sg * 8;
  int d0 = wv * 32 + dd * 4;
  int l0 = c * CH;

  const u16* fw = wdec + ((size_t)(b * LL + l0)) * DIM + h * 64 + s0;
  const u16* fB = proj + ((size_t)(b * LL + l0)) * NPROJ + 2560 + h * 64 + s0;
  const u16* fC = fB + 2560;
  const u16* fk = kb + ((size_t)(b * LL + l0)) * DIM + h * 64 + d0;
  const u16* fv = vb + ((size_t)(b * LL + l0)) * DIM + h * 64 + d0;
  u16* py = yout + ((size_t)(b * LL + l0)) * NPROJ + h * 64 + d0;

  float st[8][4];
  float pc[8];
  #pragma unroll
  for (int i = 0; i < 8; ++i) {
    pc[i] = 1.f;
    #pragma unroll
    for (int j = 0; j < 4; ++j) st[i][j] = 0.f;
  }

#define P1_DECL(n) uint4 wS##n, BS##n, CS##n; uint2 kS##n, vS##n
#define P1_LOAD(n) do { \
    wS##n = *(const uint4*)fw; BS##n = *(const uint4*)fB; \
    CS##n = *(const uint4*)fC; kS##n = *(const uint2*)fk; \
    vS##n = *(const uint2*)fv; \
    fw += DIM; fB += NPROJ; fC += NPROJ; fk += DIM; fv += DIM; } while (0)
#define P1_PROC(n) do { \
    float wv8[8], Bv[8], Cv[8], kv4[4], pr[4]; \
    wv8[0]=bflo(wS##n.x); wv8[1]=bfhi(wS##n.x); wv8[2]=bflo(wS##n.y); wv8[3]=bfhi(wS##n.y); \
    wv8[4]=bflo(wS##n.z); wv8[5]=bfhi(wS##n.z); wv8[6]=bflo(wS##n.w); wv8[7]=bfhi(wS##n.w); \
    Bv[0]=bflo(BS##n.x); Bv[1]=bfhi(BS##n.x); Bv[2]=bflo(BS##n.y); Bv[3]=bfhi(BS##n.y); \
    Bv[4]=bflo(BS##n.z); Bv[5]=bfhi(BS##n.z); Bv[6]=bflo(BS##n.w); Bv[7]=bfhi(BS##n.w); \
    Cv[0]=bflo(CS##n.x); Cv[1]=bfhi(CS##n.x); Cv[2]=bflo(CS##n.y); Cv[3]=bfhi(CS##n.y); \
    Cv[4]=bflo(CS##n.z); Cv[5]=bfhi(CS##n.z); Cv[6]=bflo(CS##n.w); Cv[7]=bfhi(CS##n.w); \
    kv4[0]=bflo(kS##n.x)*bflo(vS##n.x); kv4[1]=bfhi(kS##n.x)*bfhi(vS##n.x); \
    kv4[2]=bflo(kS##n.y)*bflo(vS##n.y); kv4[3]=bfhi(kS##n.y)*bfhi(vS##n.y); \
    pr[0]=0.f; pr[1]=0.f; pr[2]=0.f; pr[3]=0.f; \
    _Pragma("unroll") \
    for (int i = 0; i < 8; ++i) { \
      pc[i] *= wv8[i]; \
      _Pragma("unroll") \
      for (int j = 0; j < 4; ++j) { \
        st[i][j] = fmaf(wv8[i], st[i][j], Bv[i] * kv4[j]); \
        pr[j] = fmaf(st[i][j], Cv[i], pr[j]); } } \
    _Pragma("unroll") \
    for (int j = 0; j < 4; ++j) { \
      pr[j] += __shfl_xor(pr[j], 8, 64); \
      pr[j] += __shfl_xor(pr[j], 16, 64); \
      pr[j] += __shfl_xor(pr[j], 32, 64); } \
    if (lane < 8) { \
      uint2 ov; \
      ov.x = (unsigned)f2bf(pr[0]) | ((unsigned)f2bf(pr[1]) << 16); \
      ov.y = (unsigned)f2bf(pr[2]) | ((unsigned)f2bf(pr[3]) << 16); \
      *(uint2*)py = ov; } \
    py += NPROJ; } while (0)

  P1_DECL(0); P1_DECL(1); P1_DECL(2); P1_DECL(3);
  P1_LOAD(0); P1_LOAD(1); P1_LOAD(2); P1_LOAD(3);
  for (int l = 0; l < CH; l += 4) {
    P1_PROC(0); P1_LOAD(0);
    P1_PROC(1); P1_LOAD(1);
    P1_PROC(2); P1_LOAD(2);
    P1_PROC(3); P1_LOAD(3);
  }
#undef P1_DECL
#undef P1_LOAD
#undef P1_PROC

  float* Sp = Sbuf + (((size_t)c * BH + bh) * 64 + s0) * 64 + d0;
  #pragma unroll
  for (int i = 0; i < 8; ++i) {
    float4 v; v.x = st[i][0]; v.y = st[i][1]; v.z = st[i][2]; v.w = st[i][3];
    *(float4*)(Sp + (size_t)i * 64) = v;
  }
  if (wv == 0 && dd == 0) {
    #pragma unroll
    for (int i = 0; i < 8; ++i)
      Pbuf[((size_t)c * BH + bh) * 64 + s0 + i] = pc[i];
  }
}

// ---------------------------------------------------------------
__global__ __launch_bounds__(256) void scan_combine_kernel(
    float* __restrict__ Sbuf, const float* __restrict__ Pbuf,
    float* __restrict__ fstate) {
  int bh = blockIdx.x;
  int t = threadIdx.x;
  int s = t >> 2, j0 = (t & 3) * 16;
  float stin[16];
  #pragma unroll
  for (int k = 0; k < 16; ++k) stin[k] = 0.f;
  for (int c = 0; c < NC; ++c) {
    float* Sp = Sbuf + (((size_t)c * BH + bh) * 64 + s) * 64 + j0;
    float Pc = Pbuf[((size_t)c * BH + bh) * 64 + s];
    #pragma unroll
    for (int q = 0; q < 4; ++q) {
      float4 a = *(const float4*)(Sp + q * 4);
      float4 cur;
      cur.x = stin[q*4+0]; cur.y = stin[q*4+1];
      cur.z = stin[q*4+2]; cur.w = stin[q*4+3];
      *(float4*)(Sp + q * 4) = cur;           // S slot now holds st_in for chunk c
      stin[q*4+0] = a.x + Pc * stin[q*4+0];
      stin[q*4+1] = a.y + Pc * stin[q*4+1];
      stin[q*4+2] = a.z + Pc * stin[q*4+2];
      stin[q*4+3] = a.w + Pc * stin[q*4+3];
    }
  }
  float* fp = fstate + ((size_t)bh * 64 + s) * 64 + j0;
  #pragma unroll
  for (int q = 0; q < 4; ++q) {
    float4 v;
    v.x = stin[q*4+0]; v.y = stin[q*4+1];
    v.z = stin[q*4+2]; v.w = stin[q*4+3];
    *(float4*)(fp + q * 4) = v;
  }
}

// ---------------------------------------------------------------
// Phase 3 + fused gate: y_final = r * (y_local + C.(cumw*st_in)) * g
// ---------------------------------------------------------------
__global__ __launch_bounds__(128) void scan_correct_kernel(
    const u16* __restrict__ wdec, const u16* __restrict__ proj,
    const u16* __restrict__ rb, const u16* __restrict__ gb,
    const float* __restrict__ Sbuf, u16* __restrict__ yio) {
  int bx = blockIdx.x;
  int bh = bx / NC, c = bx % NC;
  int b = bh / NH, h = bh % NH;
  int wv = threadIdx.x >> 6;
  int lane = threadIdx.x & 63;
  int sg = lane >> 3, dd = lane & 7;
  int s0 = sg * 8;
  int d0 = wv * 32 + dd * 4;
  int l0 = c * CH;

  const float* Sp = Sbuf + (((size_t)c * BH + bh) * 64 + s0) * 64 + d0;
  float stin[8][4];
  #pragma unroll
  for (int i = 0; i < 8; ++i) {
    float4 v = *(const float4*)(Sp + (size_t)i * 64);
    stin[i][0] = v.x; stin[i][1] = v.y; stin[i][2] = v.z; stin[i][3] = v.w;
  }

  const u16* fw = wdec + ((size_t)(b * LL + l0)) * DIM + h * 64 + s0;
  const u16* fC = proj + ((size_t)(b * LL + l0)) * NPROJ + 5120 + h * 64 + s0;
  const u16* fy = yio  + ((size_t)(b * LL + l0)) * NPROJ + h * 64 + d0;
  const u16* fr2 = rb + ((size_t)(b * LL + l0)) * DIM + h * 64 + d0;
  const u16* fg2 = gb + ((size_t)(b * LL + l0)) * DIM + h * 64 + d0;
  u16* py = yio + ((size_t)(b * LL + l0)) * NPROJ + h * 64 + d0;

  float pc[8];
  #pragma unroll
  for (int i = 0; i < 8; ++i) pc[i] = 1.f;

#define P3_DECL(n) uint4 wT##n, CT##n; uint2 yT##n, rT##n, gT##n
#define P3_LOAD(n) do { \
    wT##n = *(const uint4*)fw; CT##n = *(const uint4*)fC; \
    yT##n = *(const uint2*)fy; rT##n = *(const uint2*)fr2; gT##n = *(const uint2*)fg2; \
    fw += DIM; fC += NPROJ; fy += NPROJ; fr2 += DIM; fg2 += DIM; } while (0)
#define P3_PROC(n) do { \
    float wv8[8], Cv[8], ac[8], pr[4]; \
    wv8[0]=bflo(wT##n.x); wv8[1]=bfhi(wT##n.x); wv8[2]=bflo(wT##n.y); wv8[3]=bfhi(wT##n.y); \
    wv8[4]=bflo(wT##n.z); wv8[5]=bfhi(wT##n.z); wv8[6]=bflo(wT##n.w); wv8[7]=bfhi(wT##n.w); \
    Cv[0]=bflo(CT##n.x); Cv[1]=bfhi(CT##n.x); Cv[2]=bflo(CT##n.y); Cv[3]=bfhi(CT##n.y); \
    Cv[4]=bflo(CT##n.z); Cv[5]=bfhi(CT##n.z); Cv[6]=bflo(CT##n.w); Cv[7]=bfhi(CT##n.w); \
    pr[0]=0.f; pr[1]=0.f; pr[2]=0.f; pr[3]=0.f; \
    _Pragma("unroll") \
    for (int i = 0; i < 8; ++i) { \
      pc[i] *= wv8[i]; ac[i] = pc[i] * Cv[i]; \
      _Pragma("unroll") \
      for (int j = 0; j < 4; ++j) pr[j] = fmaf(ac[i], stin[i][j], pr[j]); } \
    _Pragma("unroll") \
    for (int j = 0; j < 4; ++j) { \
      pr[j] += __shfl_xor(pr[j], 8, 64); \
      pr[j] += __shfl_xor(pr[j], 16, 64); \
      pr[j] += __shfl_xor(pr[j], 32, 64); } \
    if (lane < 8) { \
      float y0 = (bflo(yT##n.x) + pr[0]) * bflo(rT##n.x) * bflo(gT##n.x); \
      float y1 = (bfhi(yT##n.x) + pr[1]) * bfhi(rT##n.x) * bfhi(gT##n.x); \
      float y2 = (bflo(yT##n.y) + pr[2]) * bflo(rT##n.y) * bflo(gT##n.y); \
      float y3 = (bfhi(yT##n.y) + pr[3]) * bfhi(rT##n.y) * bfhi(gT##n.y); \
      uint2 ov; \
      ov.x = (unsigned)f2bf(y0) | ((unsigned)f2bf(y1) << 16); \
      ov.y = (unsigned)f2bf(y2) | ((unsigned)f2bf(y3) << 16); \
      *(uint2*)py = ov; } \
    py += NPROJ; } while (0)

  P3_DECL(0); P3_DECL(1); P3_DECL(2); P3_DECL(3);
  P3_LOAD(0); P3_LOAD(1); P3_LOAD(2); P3_LOAD(3);
  for (int l = 0; l < CH; l += 4) {
    P3_PROC(0); P3_LOAD(0);
    P3_PROC(1); P3_LOAD(1);
    P3_PROC(2); P3_LOAD(2);
    P3_PROC(3); P3_LOAD(3);
  }
#undef P3_DECL
#undef P3_LOAD
#undef P3_PROC
}

// ---------------------------------------------------------------
extern "C" void kernel_launch(void* const* d_in, const int* in_sizes, int n_in,
                              void* d_out, int out_size, void* d_ws, size_t ws_size,
                              hipStream_t stream) {
  const float* x    = (const float*)d_in[0];
  const float* W_r  = (const float*)d_in[1];
  const float* W_k  = (const float*)d_in[2];
  const float* W_v  = (const float*)d_in[3];
  const float* W_g  = (const float*)d_in[4];
  const float* W_xp = (const float*)d_in[5];
  const float* W_dt = (const float*)d_in[6];
  const float* b_dt = (const float*)d_in[7];
  const float* cw   = (const float*)d_in[8];
  const float* ln1g = (const float*)d_in[9];
  const float* ln1b = (const float*)d_in[10];
  const float* ln2g = (const float*)d_in[11];
  const float* ln2b = (const float*)d_in[12];
  const float* W_o  = (const float*)d_in[13];

  float* out    = (float*)d_out;
  float* fstate = out + (size_t)MTOT * DIM;

  const size_t nBL = (size_t)MTOT * DIM;
  const size_t nPJ = (size_t)MTOT * NPROJ;
  const size_t nWX = (size_t)NPROJ * DIM;
  const size_t nDD = (size_t)DIM * DIM;
  const size_t needed = (nBL * 5 + nPJ + nWX) * sizeof(u16);  // ~207 MB
  if (ws_size < needed) {
    fill_kernel<<<(out_size + 255) / 256, 256, 0, stream>>>(out, out_size, 1234.5f);
    return;
  }

  u16* wsp  = (u16*)d_ws;
  u16* x1   = wsp;
  u16* proj = x1 + nBL;
  u16* wdec = proj + nPJ;       // reused for y2 after recurrence
  u16* rb   = wdec + nBL;
  u16* gb   = rb + nBL;
  u16* kvb  = gb + nBL;         // holds k
  u16* wscr = kvb + nBL;        // weight scratch (nWX elems); scan S/P live here
  float* Sbuf = (float*)wscr;                       // NC*BH*64*64 fp32 = 21 MB
  float* Pbuf = Sbuf + (size_t)NC * BH * 64 * 64;   // NC*BH*64 fp32 = 0.3 MB

  // v output and Wv(bf16) live in d_out's `out` region (dead until the
  // final ln2 overwrites it; fstate region untouched: 5.24M+3.28M < 10.49M floats)
  u16* vscr = (u16*)d_out;        // nBL u16 = 21 MB
  u16* wvb  = vscr + nBL;         // nDD u16 = 13.1 MB

  const int nDD4 = (int)(nDD / 4);

  // 1. conv + LN1 -> x1 (bf16)
  conv_ln1_kernel<<<MTOT, 256, 0, stream>>>(x, cw, ln1g, ln1b, x1);

  // 2. proj = x1 @ W_xproj^T  (REMAP columns to [dt|B|C])
  cvt_kernel<<<2048, 256, 0, stream>>>(W_xp, wscr, NPROJ * DIM / 4);
  gemm_mfma<0,true ><<<dim3(NPROJ/128, MTOT/128), 256, 0, stream>>>(x1, DIM, wscr, nullptr, proj, NPROJ, DIM);

  // 3. w = exp(-softplus(proj_dt @ W_dt^T + b_dt))
  cvt_kernel<<<2048, 256, 0, stream>>>(W_dt, wscr, nDD4);
  gemm_mfma<2,false><<<dim3(DIM/128, MTOT/128), 256, 0, stream>>>(proj, NPROJ, wscr, b_dt, wdec, DIM, DIM);

  // 4. batched r|g|k|v GEMM (N=10240, 2560 blocks, zero tail)
  cvt_kernel<<<2048, 256, 0, stream>>>(W_r, wscr, nDD4);
  cvt_kernel<<<2048, 256, 0, stream>>>(W_g, wscr + nDD, nDD4);
  cvt_kernel<<<2048, 256, 0, stream>>>(W_k, wscr + 2 * nDD, nDD4);
  cvt_kernel<<<2048, 256, 0, stream>>>(W_v, wvb, nDD4);
  gemm_big4<<<dim3(4 * DIM / 128, MTOT / 128), 256, 0, stream>>>(
      x1, wscr, wscr + nDD, wscr + 2 * nDD, wvb, rb, gb, kvb, vscr, DIM);

  // 5. chunked scan: local (kv=k*v inline) -> combine(fstate) -> correct(+gate)
  scan_local_kernel<<<BH * NC, 128, 0, stream>>>(wdec, proj, kvb, vscr, proj, Sbuf, Pbuf);
  scan_combine_kernel<<<BH, 256, 0, stream>>>(Sbuf, Pbuf, fstate);
  scan_correct_kernel<<<BH * NC, 128, 0, stream>>>(wdec, proj, rb, gb, Sbuf, proj);

  // 6. y2 = out_inner @ W_out^T -> wdec (reuse); A = proj y-region (lda=NPROJ)
  cvt_kernel<<<2048, 256, 0, stream>>>(W_o, wscr, nDD4);
  gemm_mfma<0,false><<<dim3(DIM/128, MTOT/128), 256, 0, stream>>>(proj, NPROJ, wscr, nullptr, wdec, DIM, DIM);

  // 7. out = LN(x1 + y2) -> fp32
  ln2_kernel<<<MTOT, 256, 0, stream>>>(x1, wdec, ln2g, ln2b, out);
}

// Round 11
// 987.716 us; speedup vs baseline: 1.3162x; 1.0662x over previous
//
#include <hip/hip_runtime.h>
#include <cstddef>
#include <cstdint>

#define DIM 2560
#define NH 40
#define HDD 64
#define SD 64
#define KC 4
#define BB 2
#define LL 2048
#define MTOT (BB*LL)      // 4096
#define NPROJ (NH*3*SD)   // 7680
#define NC 16             // scan chunks
#define CH (LL/NC)        // 128 steps per chunk
#define BH (BB*NH)        // 80

typedef unsigned short u16;
typedef __attribute__((ext_vector_type(8))) short bf16x8;
typedef __attribute__((ext_vector_type(4))) float f32x4;

__device__ inline float bf2f(u16 u) { return __uint_as_float(((unsigned)u) << 16); }
__device__ inline float bflo(unsigned u) { return __uint_as_float(u << 16); }
__device__ inline float bfhi(unsigned u) { return __uint_as_float(u & 0xffff0000u); }
__device__ inline u16 f2bf(float f) {
  unsigned x = __float_as_uint(f);
  unsigned r = (x + 0x7fffu + ((x >> 16) & 1u)) >> 16;   // RNE
  return (u16)r;
}

__device__ inline void gload16(const void* g, void* lds) {
  __builtin_amdgcn_global_load_lds(
      (const __attribute__((address_space(1))) void*)g,
      (__attribute__((address_space(3))) void*)(uint32_t)(size_t)lds,
      16, 0, 0);
}

// ---------------------------------------------------------------
__global__ __launch_bounds__(256) void cvt_kernel(
    const float* __restrict__ src, u16* __restrict__ dst, int n4) {
  int i = blockIdx.x * 256 + threadIdx.x;
  int stride = gridDim.x * 256;
  for (; i < n4; i += stride) {
    float4 v = *(const float4*)(src + (size_t)i * 4);
    ushort4 o;
    o.x = f2bf(v.x); o.y = f2bf(v.y); o.z = f2bf(v.z); o.w = f2bf(v.w);
    *(ushort4*)(dst + (size_t)i * 4) = o;
  }
}

// ---------------------------------------------------------------
// 4 weights in one launch (r,g,k -> wscr slots; v -> wvb)
// ---------------------------------------------------------------
struct Cvt4Args { const float* s0; const float* s1; const float* s2; const float* s3;
                  u16* d0; u16* d1; u16* d2; u16* d3; };
__global__ __launch_bounds__(256) void cvt4_kernel(Cvt4Args a, int n4each) {
  int i = blockIdx.x * 256 + threadIdx.x;
  int stride = gridDim.x * 256;
  int total = 4 * n4each;
  for (; i < total; i += stride) {
    int which = i / n4each;
    int loc = i - which * n4each;
    const float* s = (which == 0) ? a.s0 : (which == 1) ? a.s1 : (which == 2) ? a.s2 : a.s3;
    u16* d = (which == 0) ? a.d0 : (which == 1) ? a.d1 : (which == 2) ? a.d2 : a.d3;
    float4 v = *(const float4*)(s + (size_t)loc * 4);
    ushort4 o;
    o.x = f2bf(v.x); o.y = f2bf(v.y); o.z = f2bf(v.z); o.w = f2bf(v.w);
    *(ushort4*)(d + (size_t)loc * 4) = o;
  }
}

// ---------------------------------------------------------------
__global__ __launch_bounds__(256) void fill_kernel(float* p, int n, float v) {
  int i = blockIdx.x * 256 + threadIdx.x;
  if (i < n) p[i] = v;
}

// ---------------------------------------------------------------
__device__ inline void block_reduce2(float& sum, float& sq, float* red) {
  #pragma unroll
  for (int off = 32; off; off >>= 1) {
    sum += __shfl_down(sum, off, 64);
    sq  += __shfl_down(sq,  off, 64);
  }
  int wid = threadIdx.x >> 6, lane = threadIdx.x & 63;
  if (lane == 0) { red[wid*2] = sum; red[wid*2+1] = sq; }
  __syncthreads();
  sum = red[0] + red[2] + red[4] + red[6];
  sq  = red[1] + red[3] + red[5] + red[7];
}

// ---------------------------------------------------------------
// conv (causal depthwise, K=4) + residual + LayerNorm1 -> bf16
// ---------------------------------------------------------------
__global__ __launch_bounds__(256) void conv_ln1_kernel(
    const float* __restrict__ x, const float* __restrict__ cw,
    const float* __restrict__ g1, const float* __restrict__ b1,
    u16* __restrict__ x1) {
  __shared__ float red[8];
  int bl = blockIdx.x;
  int l  = bl & (LL - 1);
  int t  = threadIdx.x;
  const float* xr = x + (size_t)bl * DIM;
  float vals[10];
  float sum = 0.f, sq = 0.f;
  #pragma unroll
  for (int i = 0; i < 10; ++i) {
    int d = t + 256 * i;
    float acc = xr[d];
    #pragma unroll
    for (int j = 0; j < KC; ++j) {
      int ll = l - (KC - 1) + j;
      if (ll >= 0) acc += x[(size_t)(bl - l + ll) * DIM + d] * cw[d * KC + j];
    }
    vals[i] = acc; sum += acc; sq += acc * acc;
  }
  block_reduce2(sum, sq, red);
  float mean = sum * (1.f / DIM);
  float var  = sq * (1.f / DIM) - mean * mean;
  float rstd = rsqrtf(var + 1e-5f);
  u16* orow = x1 + (size_t)bl * DIM;
  #pragma unroll
  for (int i = 0; i < 10; ++i) {
    int d = t + 256 * i;
    orow[d] = f2bf((vals[i] - mean) * rstd * g1[d] + b1[d]);
  }
}

// ---------------------------------------------------------------
// LN2: out = LN(x1 + y2), bf16 inputs -> fp32 out
// ---------------------------------------------------------------
__global__ __launch_bounds__(256) void ln2_kernel(
    const u16* __restrict__ x1, const u16* __restrict__ y2,
    const float* __restrict__ g2, const float* __restrict__ b2,
    float* __restrict__ out) {
  __shared__ float red[8];
  int bl = blockIdx.x;
  int t  = threadIdx.x;
  const u16* ar = x1 + (size_t)bl * DIM;
  const u16* br = y2 + (size_t)bl * DIM;
  float vals[10];
  float sum = 0.f, sq = 0.f;
  #pragma unroll
  for (int i = 0; i < 10; ++i) {
    int d = t + 256 * i;
    float v = bf2f(ar[d]) + bf2f(br[d]);
    vals[i] = v; sum += v; sq += v * v;
  }
  block_reduce2(sum, sq, red);
  float mean = sum * (1.f / DIM);
  float var  = sq * (1.f / DIM) - mean * mean;
  float rstd = rsqrtf(var + 1e-5f);
  float* orow = out + (size_t)bl * DIM;
  #pragma unroll
  for (int i = 0; i < 10; ++i) {
    int d = t + 256 * i;
    orow[d] = (vals[i] - mean) * rstd * g2[d] + b2[d];
  }
}

// ===============================================================
// Pipelined MFMA bf16 GEMM core (T3-min + T4 counted vmcnt + T5):
// double LDS buffer; raw s_barrier; s_waitcnt vmcnt(4) steady state
// (tile t+1's 4 loads stay in flight across the barrier);
// STAGE(t+2) issued after close barrier; setprio around MFMA.
// Schedule invariant (per-wave vmcnt): at iter t only stage(t+1)'s
// 4 loads are newer than stage(t) -> vmcnt(4) guarantees tile t
// resident; buffer buf[t&1] is re-staged only after the close
// barrier of the iteration that read it.
// ===============================================================
#define GEMM_PIPE_LOOP(STAGEM) \
  STAGEM(0, 0); \
  STAGEM(1, 32); \
  { \
    int nt = K / 32; \
    for (int tt = 0; tt < nt; ++tt) { \
      if (tt == nt - 1) { asm volatile("s_waitcnt vmcnt(0)" ::: "memory"); } \
      else              { asm volatile("s_waitcnt vmcnt(4)" ::: "memory"); } \
      __builtin_amdgcn_sched_barrier(0); \
      __builtin_amdgcn_s_barrier(); \
      __builtin_amdgcn_sched_barrier(0); \
      int buf = tt & 1; \
      bf16x8 a[4], b[4]; \
      _Pragma("unroll") \
      for (int i = 0; i < 4; ++i) a[i] = *(const bf16x8*)(rA + buf * 4096 + i * 16 * 32); \
      _Pragma("unroll") \
      for (int j = 0; j < 4; ++j) b[j] = *(const bf16x8*)(rB + buf * 4096 + j * 16 * 32); \
      __builtin_amdgcn_s_setprio(1); \
      _Pragma("unroll") \
      for (int i = 0; i < 4; ++i) \
        _Pragma("unroll") \
        for (int j = 0; j < 4; ++j) \
          acc[i][j] = __builtin_amdgcn_mfma_f32_16x16x32_bf16(a[i], b[j], acc[i][j], 0, 0, 0); \
      __builtin_amdgcn_s_setprio(0); \
      __builtin_amdgcn_sched_barrier(0); \
      __builtin_amdgcn_s_barrier(); \
      __builtin_amdgcn_sched_barrier(0); \
      if (tt + 2 < nt) { int k2 = (tt + 2) * 32; STAGEM(buf, k2); } \
    } \
  }

// ---------------------------------------------------------------
// EPI: 0 plain | 2 decay sigmoid(-(v+bias))
// ---------------------------------------------------------------
template<int EPI, bool REMAP>
__global__ __launch_bounds__(256) void gemm_mfma(
    const u16* __restrict__ A, int lda,
    const u16* __restrict__ Wb,
    const float* __restrict__ bias,
    u16* __restrict__ C1, int ldc,
    int K) {
  __shared__ u16 As[2 * 128 * 32];
  __shared__ u16 Bs[2 * 128 * 32];
  int t = threadIdx.x;
  int w = t >> 6, l = t & 63;
  int wr = w >> 1, wc = w & 1;
  int m0 = blockIdx.y * 128;
  int n0 = blockIdx.x * 128;

  f32x4 acc[4][4];
  #pragma unroll
  for (int i = 0; i < 4; ++i)
    #pragma unroll
    for (int j = 0; j < 4; ++j)
      acc[i][j] = (f32x4){0.f, 0.f, 0.f, 0.f};

  int srow = 32 * w + (l >> 2);
  int scol = (l & 3) * 8;
  const u16* gA = A  + (size_t)(m0 + srow) * lda + scol;
  const u16* gB = Wb + (size_t)(n0 + srow) * K   + scol;
  int ldsOff = (32 * w) * 32;

  int fr = l & 15;
  int kc = (l >> 4) * 8;
  const u16* rA = As + (size_t)(wr * 64 + fr) * 32 + kc;
  const u16* rB = Bs + (size_t)(wc * 64 + fr) * 32 + kc;

#define STAGE_S(buf, k0) do { \
    gload16(gA + (k0), As + (buf) * 4096 + ldsOff); \
    gload16(gA + (size_t)16 * lda + (k0), As + (buf) * 4096 + ldsOff + 16 * 32); \
    gload16(gB + (k0), Bs + (buf) * 4096 + ldsOff); \
    gload16(gB + (size_t)16 * K + (k0), Bs + (buf) * 4096 + ldsOff + 16 * 32); } while (0)

  GEMM_PIPE_LOOP(STAGE_S)
#undef STAGE_S

  int crow = (l >> 4) * 4;
  int ccol = l & 15;
  #pragma unroll
  for (int j = 0; j < 4; ++j) {
    int col = n0 + wc * 64 + j * 16 + ccol;
    int colr = col;
    if (REMAP) {
      int h = col / 192, r3 = col % 192;
      colr = (r3 / 64) * 2560 + h * 64 + (r3 & 63);
    }
    float bv = (EPI == 2) ? bias[col] : 0.f;
    #pragma unroll
    for (int i = 0; i < 4; ++i) {
      #pragma unroll
      for (int q = 0; q < 4; ++q) {
        int row = m0 + wr * 64 + i * 16 + crow + q;
        float v = acc[i][j][q];
        if constexpr (EPI == 2) v = 1.f / (1.f + expf(v + bv));
        C1[(size_t)row * ldc + colr] = f2bf(v);
      }
    }
  }
}

// ---------------------------------------------------------------
// Batched 4-way GEMM (r|g|k|v), pipelined core, same as round 10
// otherwise. grid 80x32 = 2560 blocks.
// ---------------------------------------------------------------
__global__ __launch_bounds__(256) void gemm_big4(
    const u16* __restrict__ A,
    const u16* __restrict__ W0, const u16* __restrict__ W1,
    const u16* __restrict__ W2, const u16* __restrict__ W3,
    u16* __restrict__ C0, u16* __restrict__ C1b,
    u16* __restrict__ C2, u16* __restrict__ C3,
    int K) {
  __shared__ u16 As[2 * 128 * 32];
  __shared__ u16 Bs[2 * 128 * 32];
  int t = threadIdx.x;
  int w = t >> 6, l = t & 63;
  int wr = w >> 1, wc = w & 1;
  int m0 = blockIdx.y * 128;
  int n0g = blockIdx.x * 128;
  int which = n0g / 2560;
  int n0 = n0g - which * 2560;
  const u16* Wsel = (which == 0) ? W0 : (which == 1) ? W1 : (which == 2) ? W2 : W3;
  u16* Csel = (which == 0) ? C0 : (which == 1) ? C1b : (which == 2) ? C2 : C3;
  bool sig = (which < 2);

  f32x4 acc[4][4];
  #pragma unroll
  for (int i = 0; i < 4; ++i)
    #pragma unroll
    for (int j = 0; j < 4; ++j)
      acc[i][j] = (f32x4){0.f, 0.f, 0.f, 0.f};

  int srow = 32 * w + (l >> 2);
  int scol = (l & 3) * 8;
  const u16* gA = A    + (size_t)(m0 + srow) * K + scol;
  const u16* gB = Wsel + (size_t)(n0 + srow) * K + scol;
  int ldsOff = (32 * w) * 32;

  int fr = l & 15;
  int kc = (l >> 4) * 8;
  const u16* rA = As + (size_t)(wr * 64 + fr) * 32 + kc;
  const u16* rB = Bs + (size_t)(wc * 64 + fr) * 32 + kc;

#define STAGE_B(buf, k0) do { \
    gload16(gA + (k0), As + (buf) * 4096 + ldsOff); \
    gload16(gA + (size_t)16 * K + (k0), As + (buf) * 4096 + ldsOff + 16 * 32); \
    gload16(gB + (k0), Bs + (buf) * 4096 + ldsOff); \
    gload16(gB + (size_t)16 * K + (k0), Bs + (buf) * 4096 + ldsOff + 16 * 32); } while (0)

  GEMM_PIPE_LOOP(STAGE_B)
#undef STAGE_B

  int crow = (l >> 4) * 4;
  int ccol = l & 15;
  #pragma unroll
  for (int j = 0; j < 4; ++j) {
    int col = n0 + wc * 64 + j * 16 + ccol;
    #pragma unroll
    for (int i = 0; i < 4; ++i) {
      #pragma unroll
      for (int q = 0; q < 4; ++q) {
        int row = m0 + wr * 64 + i * 16 + crow + q;
        float v = acc[i][j][q];
        if (sig) v = 1.f / (1.f + expf(-v));
        Csel[(size_t)row * DIM + col] = f2bf(v);
      }
    }
  }
}

// ===============================================================
// Chunked parallel scan (round-10 structure, unchanged).
// ===============================================================
__global__ __launch_bounds__(128) void scan_local_kernel(
    const u16* __restrict__ wdec, const u16* __restrict__ proj,
    const u16* __restrict__ kb, const u16* __restrict__ vb,
    u16* __restrict__ yout,
    float* __restrict__ Sbuf, float* __restrict__ Pbuf) {
  int bx = blockIdx.x;
  int bh = bx / NC, c = bx % NC;
  int b = bh / NH, h = bh % NH;
  int wv = threadIdx.x >> 6;
  int lane = threadIdx.x & 63;
  int sg = lane >> 3, dd = lane & 7;
  int s0 = sg * 8;
  int d0 = wv * 32 + dd * 4;
  int l0 = c * CH;

  const u16* fw = wdec + ((size_t)(b * LL + l0)) * DIM + h * 64 + s0;
  const u16* fB = proj + ((size_t)(b * LL + l0)) * NPROJ + 2560 + h * 64 + s0;
  const u16* fC = fB + 2560;
  const u16* fk = kb + ((size_t)(b * LL + l0)) * DIM + h * 64 + d0;
  const u16* fv = vb + ((size_t)(b * LL + l0)) * DIM + h * 64 + d0;
  u16* py = yout + ((size_t)(b * LL + l0)) * NPROJ + h * 64 + d0;

  float st[8][4];
  float pc[8];
  #pragma unroll
  for (int i = 0; i < 8; ++i) {
    pc[i] = 1.f;
    #pragma unroll
    for (int j = 0; j < 4; ++j) st[i][j] = 0.f;
  }

#define P1_DECL(n) uint4 wS##n, BS##n, CS##n; uint2 kS##n, vS##n
#define P1_LOAD(n) do { \
    wS##n = *(const uint4*)fw; BS##n = *(const uint4*)fB; \
    CS##n = *(const uint4*)fC; kS##n = *(const uint2*)fk; \
    vS##n = *(const uint2*)fv; \
    fw += DIM; fB += NPROJ; fC += NPROJ; fk += DIM; fv += DIM; } while (0)
#define P1_PROC(n) do { \
    float wv8[8], Bv[8], Cv[8], kv4[4], pr[4]; \
    wv8[0]=bflo(wS##n.x); wv8[1]=bfhi(wS##n.x); wv8[2]=bflo(wS##n.y); wv8[3]=bfhi(wS##n.y); \
    wv8[4]=bflo(wS##n.z); wv8[5]=bfhi(wS##n.z); wv8[6]=bflo(wS##n.w); wv8[7]=bfhi(wS##n.w); \
    Bv[0]=bflo(BS##n.x); Bv[1]=bfhi(BS##n.x); Bv[2]=bflo(BS##n.y); Bv[3]=bfhi(BS##n.y); \
    Bv[4]=bflo(BS##n.z); Bv[5]=bfhi(BS##n.z); Bv[6]=bflo(BS##n.w); Bv[7]=bfhi(BS##n.w); \
    Cv[0]=bflo(CS##n.x); Cv[1]=bfhi(CS##n.x); Cv[2]=bflo(CS##n.y); Cv[3]=bfhi(CS##n.y); \
    Cv[4]=bflo(CS##n.z); Cv[5]=bfhi(CS##n.z); Cv[6]=bflo(CS##n.w); Cv[7]=bfhi(CS##n.w); \
    kv4[0]=bflo(kS##n.x)*bflo(vS##n.x); kv4[1]=bfhi(kS##n.x)*bfhi(vS##n.x); \
    kv4[2]=bflo(kS##n.y)*bflo(vS##n.y); kv4[3]=bfhi(kS##n.y)*bfhi(vS##n.y); \
    pr[0]=0.f; pr[1]=0.f; pr[2]=0.f; pr[3]=0.f; \
    _Pragma("unroll") \
    for (int i = 0; i < 8; ++i) { \
      pc[i] *= wv8[i]; \
      _Pragma("unroll") \
      for (int j = 0; j < 4; ++j) { \
        st[i][j] = fmaf(wv8[i], st[i][j], Bv[i] * kv4[j]); \
        pr[j] = fmaf(st[i][j], Cv[i], pr[j]); } } \
    _Pragma("unroll") \
    for (int j = 0; j < 4; ++j) { \
      pr[j] += __shfl_xor(pr[j], 8, 64); \
      pr[j] += __shfl_xor(pr[j], 16, 64); \
      pr[j] += __shfl_xor(pr[j], 32, 64); } \
    if (lane < 8) { \
      uint2 ov; \
      ov.x = (unsigned)f2bf(pr[0]) | ((unsigned)f2bf(pr[1]) << 16); \
      ov.y = (unsigned)f2bf(pr[2]) | ((unsigned)f2bf(pr[3]) << 16); \
      *(uint2*)py = ov; } \
    py += NPROJ; } while (0)

  P1_DECL(0); P1_DECL(1); P1_DECL(2); P1_DECL(3);
  P1_LOAD(0); P1_LOAD(1); P1_LOAD(2); P1_LOAD(3);
  for (int l = 0; l < CH; l += 4) {
    P1_PROC(0); P1_LOAD(0);
    P1_PROC(1); P1_LOAD(1);
    P1_PROC(2); P1_LOAD(2);
    P1_PROC(3); P1_LOAD(3);
  }
#undef P1_DECL
#undef P1_LOAD
#undef P1_PROC

  float* Sp = Sbuf + (((size_t)c * BH + bh) * 64 + s0) * 64 + d0;
  #pragma unroll
  for (int i = 0; i < 8; ++i) {
    float4 v; v.x = st[i][0]; v.y = st[i][1]; v.z = st[i][2]; v.w = st[i][3];
    *(float4*)(Sp + (size_t)i * 64) = v;
  }
  if (wv == 0 && dd == 0) {
    #pragma unroll
    for (int i = 0; i < 8; ++i)
      Pbuf[((size_t)c * BH + bh) * 64 + s0 + i] = pc[i];
  }
}

// ---------------------------------------------------------------
__global__ __launch_bounds__(256) void scan_combine_kernel(
    float* __restrict__ Sbuf, const float* __restrict__ Pbuf,
    float* __restrict__ fstate) {
  int bh = blockIdx.x;
  int t = threadIdx.x;
  int s = t >> 2, j0 = (t & 3) * 16;
  float stin[16];
  #pragma unroll
  for (int k = 0; k < 16; ++k) stin[k] = 0.f;
  for (int c = 0; c < NC; ++c) {
    float* Sp = Sbuf + (((size_t)c * BH + bh) * 64 + s) * 64 + j0;
    float Pc = Pbuf[((size_t)c * BH + bh) * 64 + s];
    #pragma unroll
    for (int q = 0; q < 4; ++q) {
      float4 a = *(const float4*)(Sp + q * 4);
      float4 cur;
      cur.x = stin[q*4+0]; cur.y = stin[q*4+1];
      cur.z = stin[q*4+2]; cur.w = stin[q*4+3];
      *(float4*)(Sp + q * 4) = cur;           // S slot now holds st_in for chunk c
      stin[q*4+0] = a.x + Pc * stin[q*4+0];
      stin[q*4+1] = a.y + Pc * stin[q*4+1];
      stin[q*4+2] = a.z + Pc * stin[q*4+2];
      stin[q*4+3] = a.w + Pc * stin[q*4+3];
    }
  }
  float* fp = fstate + ((size_t)bh * 64 + s) * 64 + j0;
  #pragma unroll
  for (int q = 0; q < 4; ++q) {
    float4 v;
    v.x = stin[q*4+0]; v.y = stin[q*4+1];
    v.z = stin[q*4+2]; v.w = stin[q*4+3];
    *(float4*)(fp + q * 4) = v;
  }
}

// ---------------------------------------------------------------
// Phase 3 + fused gate: y_final = r * (y_local + C.(cumw*st_in)) * g
// ---------------------------------------------------------------
__global__ __launch_bounds__(128) void scan_correct_kernel(
    const u16* __restrict__ wdec, const u16* __restrict__ proj,
    const u16* __restrict__ rb, const u16* __restrict__ gb,
    const float* __restrict__ Sbuf, u16* __restrict__ yio) {
  int bx = blockIdx.x;
  int bh = bx / NC, c = bx % NC;
  int b = bh / NH, h = bh % NH;
  int wv = threadIdx.x >> 6;
  int lane = threadIdx.x & 63;
  int sg = lane >> 3, dd = lane & 7;
  int s0 = sg * 8;
  int d0 = wv * 32 + dd * 4;
  int l0 = c * CH;

  const float* Sp = Sbuf + (((size_t)c * BH + bh) * 64 + s0) * 64 + d0;
  float stin[8][4];
  #pragma unroll
  for (int i = 0; i < 8; ++i) {
    float4 v = *(const float4*)(Sp + (size_t)i * 64);
    stin[i][0] = v.x; stin[i][1] = v.y; stin[i][2] = v.z; stin[i][3] = v.w;
  }

  const u16* fw = wdec + ((size_t)(b * LL + l0)) * DIM + h * 64 + s0;
  const u16* fC = proj + ((size_t)(b * LL + l0)) * NPROJ + 5120 + h * 64 + s0;
  const u16* fy = yio  + ((size_t)(b * LL + l0)) * NPROJ + h * 64 + d0;
  const u16* fr2 = rb + ((size_t)(b * LL + l0)) * DIM + h * 64 + d0;
  const u16* fg2 = gb + ((size_t)(b * LL + l0)) * DIM + h * 64 + d0;
  u16* py = yio + ((size_t)(b * LL + l0)) * NPROJ + h * 64 + d0;

  float pc[8];
  #pragma unroll
  for (int i = 0; i < 8; ++i) pc[i] = 1.f;

#define P3_DECL(n) uint4 wT##n, CT##n; uint2 yT##n, rT##n, gT##n
#define P3_LOAD(n) do { \
    wT##n = *(const uint4*)fw; CT##n = *(const uint4*)fC; \
    yT##n = *(const uint2*)fy; rT##n = *(const uint2*)fr2; gT##n = *(const uint2*)fg2; \
    fw += DIM; fC += NPROJ; fy += NPROJ; fr2 += DIM; fg2 += DIM; } while (0)
#define P3_PROC(n) do { \
    float wv8[8], Cv[8], ac[8], pr[4]; \
    wv8[0]=bflo(wT##n.x); wv8[1]=bfhi(wT##n.x); wv8[2]=bflo(wT##n.y); wv8[3]=bfhi(wT##n.y); \
    wv8[4]=bflo(wT##n.z); wv8[5]=bfhi(wT##n.z); wv8[6]=bflo(wT##n.w); wv8[7]=bfhi(wT##n.w); \
    Cv[0]=bflo(CT##n.x); Cv[1]=bfhi(CT##n.x); Cv[2]=bflo(CT##n.y); Cv[3]=bfhi(CT##n.y); \
    Cv[4]=bflo(CT##n.z); Cv[5]=bfhi(CT##n.z); Cv[6]=bflo(CT##n.w); Cv[7]=bfhi(CT##n.w); \
    pr[0]=0.f; pr[1]=0.f; pr[2]=0.f; pr[3]=0.f; \
    _Pragma("unroll") \
    for (int i = 0; i < 8; ++i) { \
      pc[i] *= wv8[i]; ac[i] = pc[i] * Cv[i]; \
      _Pragma("unroll") \
      for (int j = 0; j < 4; ++j) pr[j] = fmaf(ac[i], stin[i][j], pr[j]); } \
    _Pragma("unroll") \
    for (int j = 0; j < 4; ++j) { \
      pr[j] += __shfl_xor(pr[j], 8, 64); \
      pr[j] += __shfl_xor(pr[j], 16, 64); \
      pr[j] += __shfl_xor(pr[j], 32, 64); } \
    if (lane < 8) { \
      float y0 = (bflo(yT##n.x) + pr[0]) * bflo(rT##n.x) * bflo(gT##n.x); \
      float y1 = (bfhi(yT##n.x) + pr[1]) * bfhi(rT##n.x) * bfhi(gT##n.x); \
      float y2 = (bflo(yT##n.y) + pr[2]) * bflo(rT##n.y) * bflo(gT##n.y); \
      float y3 = (bfhi(yT##n.y) + pr[3]) * bfhi(rT##n.y) * bfhi(gT##n.y); \
      uint2 ov; \
      ov.x = (unsigned)f2bf(y0) | ((unsigned)f2bf(y1) << 16); \
      ov.y = (unsigned)f2bf(y2) | ((unsigned)f2bf(y3) << 16); \
      *(uint2*)py = ov; } \
    py += NPROJ; } while (0)

  P3_DECL(0); P3_DECL(1); P3_DECL(2); P3_DECL(3);
  P3_LOAD(0); P3_LOAD(1); P3_LOAD(2); P3_LOAD(3);
  for (int l = 0; l < CH; l += 4) {
    P3_PROC(0); P3_LOAD(0);
    P3_PROC(1); P3_LOAD(1);
    P3_PROC(2); P3_LOAD(2);
    P3_PROC(3); P3_LOAD(3);
  }
#undef P3_DECL
#undef P3_LOAD
#undef P3_PROC
}

// ---------------------------------------------------------------
extern "C" void kernel_launch(void* const* d_in, const int* in_sizes, int n_in,
                              void* d_out, int out_size, void* d_ws, size_t ws_size,
                              hipStream_t stream) {
  const float* x    = (const float*)d_in[0];
  const float* W_r  = (const float*)d_in[1];
  const float* W_k  = (const float*)d_in[2];
  const float* W_v  = (const float*)d_in[3];
  const float* W_g  = (const float*)d_in[4];
  const float* W_xp = (const float*)d_in[5];
  const float* W_dt = (const float*)d_in[6];
  const float* b_dt = (const float*)d_in[7];
  const float* cw   = (const float*)d_in[8];
  const float* ln1g = (const float*)d_in[9];
  const float* ln1b = (const float*)d_in[10];
  const float* ln2g = (const float*)d_in[11];
  const float* ln2b = (const float*)d_in[12];
  const float* W_o  = (const float*)d_in[13];

  float* out    = (float*)d_out;
  float* fstate = out + (size_t)MTOT * DIM;

  const size_t nBL = (size_t)MTOT * DIM;
  const size_t nPJ = (size_t)MTOT * NPROJ;
  const size_t nWX = (size_t)NPROJ * DIM;
  const size_t nDD = (size_t)DIM * DIM;
  const size_t needed = (nBL * 5 + nPJ + nWX) * sizeof(u16);  // ~207 MB
  if (ws_size < needed) {
    fill_kernel<<<(out_size + 255) / 256, 256, 0, stream>>>(out, out_size, 1234.5f);
    return;
  }

  u16* wsp  = (u16*)d_ws;
  u16* x1   = wsp;
  u16* proj = x1 + nBL;
  u16* wdec = proj + nPJ;       // reused for y2 after recurrence
  u16* rb   = wdec + nBL;
  u16* gb   = rb + nBL;
  u16* kvb  = gb + nBL;         // holds k
  u16* wscr = kvb + nBL;        // weight scratch (nWX elems); scan S/P live here
  float* Sbuf = (float*)wscr;                       // NC*BH*64*64 fp32 = 21 MB
  float* Pbuf = Sbuf + (size_t)NC * BH * 64 * 64;   // NC*BH*64 fp32 = 0.3 MB

  // v output and Wv(bf16) live in d_out's `out` region (dead until ln2;
  // fstate region untouched: 5.24M+3.28M < 10.49M floats)
  u16* vscr = (u16*)d_out;        // nBL u16 = 21 MB
  u16* wvb  = vscr + nBL;         // nDD u16 = 13.1 MB

  const int nDD4 = (int)(nDD / 4);

  // 1. conv + LN1 -> x1 (bf16)
  conv_ln1_kernel<<<MTOT, 256, 0, stream>>>(x, cw, ln1g, ln1b, x1);

  // 2. proj = x1 @ W_xproj^T  (REMAP columns to [dt|B|C])
  cvt_kernel<<<2048, 256, 0, stream>>>(W_xp, wscr, NPROJ * DIM / 4);
  gemm_mfma<0,true ><<<dim3(NPROJ/128, MTOT/128), 256, 0, stream>>>(x1, DIM, wscr, nullptr, proj, NPROJ, DIM);

  // 3. w = exp(-softplus(proj_dt @ W_dt^T + b_dt))
  cvt_kernel<<<2048, 256, 0, stream>>>(W_dt, wscr, nDD4);
  gemm_mfma<2,false><<<dim3(DIM/128, MTOT/128), 256, 0, stream>>>(proj, NPROJ, wscr, b_dt, wdec, DIM, DIM);

  // 4. batched r|g|k|v GEMM (one cvt launch + one GEMM launch)
  Cvt4Args ca;
  ca.s0 = W_r; ca.s1 = W_g; ca.s2 = W_k; ca.s3 = W_v;
  ca.d0 = wscr; ca.d1 = wscr + nDD; ca.d2 = wscr + 2 * nDD; ca.d3 = wvb;
  cvt4_kernel<<<2048, 256, 0, stream>>>(ca, nDD4);
  gemm_big4<<<dim3(4 * DIM / 128, MTOT / 128), 256, 0, stream>>>(
      x1, wscr, wscr + nDD, wscr + 2 * nDD, wvb, rb, gb, kvb, vscr, DIM);

  // 5. chunked scan: local (kv=k*v inline) -> combine(fstate) -> correct(+gate)
  scan_local_kernel<<<BH * NC, 128, 0, stream>>>(wdec, proj, kvb, vscr, proj, Sbuf, Pbuf);
  scan_combine_kernel<<<BH, 256, 0, stream>>>(Sbuf, Pbuf, fstate);
  scan_correct_kernel<<<BH * NC, 128, 0, stream>>>(wdec, proj, rb, gb, Sbuf, proj);

  // 6. y2 = out_inner @ W_out^T -> wdec (reuse); A = proj y-region (lda=NPROJ)
  cvt_kernel<<<2048, 256, 0, stream>>>(W_o, wscr, nDD4);
  gemm_mfma<0,false><<<dim3(DIM/128, MTOT/128), 256, 0, stream>>>(proj, NPROJ, wscr, nullptr, wdec, DIM, DIM);

  // 7. out = LN(x1 + y2) -> fp32
  ln2_kernel<<<MTOT, 256, 0, stream>>>(x1, wdec, ln2g, ln2b, out);
}

// Round 12
// 895.728 us; speedup vs baseline: 1.4513x; 1.1027x over previous
//
#include <hip/hip_runtime.h>
#include <cstddef>
#include <cstdint>

#define DIM 2560
#define NH 40
#define HDD 64
#define SD 64
#define KC 4
#define BB 2
#define LL 2048
#define MTOT (BB*LL)      // 4096
#define NPROJ (NH*3*SD)   // 7680
#define NC 16             // scan chunks
#define CH (LL/NC)        // 128 steps per chunk
#define BH (BB*NH)        // 80

typedef unsigned short u16;
typedef __attribute__((ext_vector_type(8))) short bf16x8;
typedef __attribute__((ext_vector_type(4))) float f32x4;

__device__ inline float bf2f(u16 u) { return __uint_as_float(((unsigned)u) << 16); }
__device__ inline float bflo(unsigned u) { return __uint_as_float(u << 16); }
__device__ inline float bfhi(unsigned u) { return __uint_as_float(u & 0xffff0000u); }
__device__ inline u16 f2bf(float f) {
  unsigned x = __float_as_uint(f);
  unsigned r = (x + 0x7fffu + ((x >> 16) & 1u)) >> 16;   // RNE
  return (u16)r;
}

__device__ inline void gload16(const void* g, void* lds) {
  __builtin_amdgcn_global_load_lds(
      (const __attribute__((address_space(1))) void*)g,
      (__attribute__((address_space(3))) void*)(uint32_t)(size_t)lds,
      16, 0, 0);
}

// ---------------------------------------------------------------
__global__ __launch_bounds__(256) void cvt_kernel(
    const float* __restrict__ src, u16* __restrict__ dst, int n4) {
  int i = blockIdx.x * 256 + threadIdx.x;
  int stride = gridDim.x * 256;
  for (; i < n4; i += stride) {
    float4 v = *(const float4*)(src + (size_t)i * 4);
    ushort4 o;
    o.x = f2bf(v.x); o.y = f2bf(v.y); o.z = f2bf(v.z); o.w = f2bf(v.w);
    *(ushort4*)(dst + (size_t)i * 4) = o;
  }
}

// ---------------------------------------------------------------
struct Cvt4Args { const float* s0; const float* s1; const float* s2; const float* s3;
                  u16* d0; u16* d1; u16* d2; u16* d3; };
__global__ __launch_bounds__(256) void cvt4_kernel(Cvt4Args a, int n4each) {
  int i = blockIdx.x * 256 + threadIdx.x;
  int stride = gridDim.x * 256;
  int total = 4 * n4each;
  for (; i < total; i += stride) {
    int which = i / n4each;
    int loc = i - which * n4each;
    const float* s = (which == 0) ? a.s0 : (which == 1) ? a.s1 : (which == 2) ? a.s2 : a.s3;
    u16* d = (which == 0) ? a.d0 : (which == 1) ? a.d1 : (which == 2) ? a.d2 : a.d3;
    float4 v = *(const float4*)(s + (size_t)loc * 4);
    ushort4 o;
    o.x = f2bf(v.x); o.y = f2bf(v.y); o.z = f2bf(v.z); o.w = f2bf(v.w);
    *(ushort4*)(d + (size_t)loc * 4) = o;
  }
}

// ---------------------------------------------------------------
__global__ __launch_bounds__(256) void fill_kernel(float* p, int n, float v) {
  int i = blockIdx.x * 256 + threadIdx.x;
  if (i < n) p[i] = v;
}

// ---------------------------------------------------------------
__device__ inline void block_reduce2(float& sum, float& sq, float* red) {
  #pragma unroll
  for (int off = 32; off; off >>= 1) {
    sum += __shfl_down(sum, off, 64);
    sq  += __shfl_down(sq,  off, 64);
  }
  int wid = threadIdx.x >> 6, lane = threadIdx.x & 63;
  if (lane == 0) { red[wid*2] = sum; red[wid*2+1] = sq; }
  __syncthreads();
  sum = red[0] + red[2] + red[4] + red[6];
  sq  = red[1] + red[3] + red[5] + red[7];
}

// ---------------------------------------------------------------
// conv (causal depthwise, K=4) + residual + LayerNorm1 -> bf16
// ---------------------------------------------------------------
__global__ __launch_bounds__(256) void conv_ln1_kernel(
    const float* __restrict__ x, const float* __restrict__ cw,
    const float* __restrict__ g1, const float* __restrict__ b1,
    u16* __restrict__ x1) {
  __shared__ float red[8];
  int bl = blockIdx.x;
  int l  = bl & (LL - 1);
  int t  = threadIdx.x;
  const float* xr = x + (size_t)bl * DIM;
  float vals[10];
  float sum = 0.f, sq = 0.f;
  #pragma unroll
  for (int i = 0; i < 10; ++i) {
    int d = t + 256 * i;
    float acc = xr[d];
    #pragma unroll
    for (int j = 0; j < KC; ++j) {
      int ll = l - (KC - 1) + j;
      if (ll >= 0) acc += x[(size_t)(bl - l + ll) * DIM + d] * cw[d * KC + j];
    }
    vals[i] = acc; sum += acc; sq += acc * acc;
  }
  block_reduce2(sum, sq, red);
  float mean = sum * (1.f / DIM);
  float var  = sq * (1.f / DIM) - mean * mean;
  float rstd = rsqrtf(var + 1e-5f);
  u16* orow = x1 + (size_t)bl * DIM;
  #pragma unroll
  for (int i = 0; i < 10; ++i) {
    int d = t + 256 * i;
    orow[d] = f2bf((vals[i] - mean) * rstd * g1[d] + b1[d]);
  }
}

// ---------------------------------------------------------------
// LN2: out = LN(x1 + y2), bf16 inputs -> fp32 out
// ---------------------------------------------------------------
__global__ __launch_bounds__(256) void ln2_kernel(
    const u16* __restrict__ x1, const u16* __restrict__ y2,
    const float* __restrict__ g2, const float* __restrict__ b2,
    float* __restrict__ out) {
  __shared__ float red[8];
  int bl = blockIdx.x;
  int t  = threadIdx.x;
  const u16* ar = x1 + (size_t)bl * DIM;
  const u16* br = y2 + (size_t)bl * DIM;
  float vals[10];
  float sum = 0.f, sq = 0.f;
  #pragma unroll
  for (int i = 0; i < 10; ++i) {
    int d = t + 256 * i;
    float v = bf2f(ar[d]) + bf2f(br[d]);
    vals[i] = v; sum += v; sq += v * v;
  }
  block_reduce2(sum, sq, red);
  float mean = sum * (1.f / DIM);
  float var  = sq * (1.f / DIM) - mean * mean;
  float rstd = rsqrtf(var + 1e-5f);
  float* orow = out + (size_t)bl * DIM;
  #pragma unroll
  for (int i = 0; i < 10; ++i) {
    int d = t + 256 * i;
    orow[d] = (vals[i] - mean) * rstd * g2[d] + b2[d];
  }
}

// ===============================================================
// 128^2 pipelined MFMA core (round-11, proven) for dt / Wout.
// ===============================================================
#define GEMM_PIPE_LOOP(STAGEM) \
  STAGEM(0, 0); \
  STAGEM(1, 32); \
  { \
    int nt = K / 32; \
    for (int tt = 0; tt < nt; ++tt) { \
      if (tt == nt - 1) { asm volatile("s_waitcnt vmcnt(0)" ::: "memory"); } \
      else              { asm volatile("s_waitcnt vmcnt(4)" ::: "memory"); } \
      __builtin_amdgcn_sched_barrier(0); \
      __builtin_amdgcn_s_barrier(); \
      __builtin_amdgcn_sched_barrier(0); \
      int buf = tt & 1; \
      bf16x8 a[4], b[4]; \
      _Pragma("unroll") \
      for (int i = 0; i < 4; ++i) a[i] = *(const bf16x8*)(rA + buf * 4096 + i * 16 * 32); \
      _Pragma("unroll") \
      for (int j = 0; j < 4; ++j) b[j] = *(const bf16x8*)(rB + buf * 4096 + j * 16 * 32); \
      __builtin_amdgcn_s_setprio(1); \
      _Pragma("unroll") \
      for (int i = 0; i < 4; ++i) \
        _Pragma("unroll") \
        for (int j = 0; j < 4; ++j) \
          acc[i][j] = __builtin_amdgcn_mfma_f32_16x16x32_bf16(a[i], b[j], acc[i][j], 0, 0, 0); \
      __builtin_amdgcn_s_setprio(0); \
      __builtin_amdgcn_sched_barrier(0); \
      __builtin_amdgcn_s_barrier(); \
      __builtin_amdgcn_sched_barrier(0); \
      if (tt + 2 < nt) { int k2 = (tt + 2) * 32; STAGEM(buf, k2); } \
    } \
  }

template<int EPI, bool REMAP>
__global__ __launch_bounds__(256) void gemm_mfma(
    const u16* __restrict__ A, int lda,
    const u16* __restrict__ Wb,
    const float* __restrict__ bias,
    u16* __restrict__ C1, int ldc,
    int K) {
  __shared__ u16 As[2 * 128 * 32];
  __shared__ u16 Bs[2 * 128 * 32];
  int t = threadIdx.x;
  int w = t >> 6, l = t & 63;
  int wr = w >> 1, wc = w & 1;
  int m0 = blockIdx.y * 128;
  int n0 = blockIdx.x * 128;

  f32x4 acc[4][4];
  #pragma unroll
  for (int i = 0; i < 4; ++i)
    #pragma unroll
    for (int j = 0; j < 4; ++j)
      acc[i][j] = (f32x4){0.f, 0.f, 0.f, 0.f};

  int srow = 32 * w + (l >> 2);
  int scol = (l & 3) * 8;
  const u16* gA = A  + (size_t)(m0 + srow) * lda + scol;
  const u16* gB = Wb + (size_t)(n0 + srow) * K   + scol;
  int ldsOff = (32 * w) * 32;

  int fr = l & 15;
  int kc = (l >> 4) * 8;
  const u16* rA = As + (size_t)(wr * 64 + fr) * 32 + kc;
  const u16* rB = Bs + (size_t)(wc * 64 + fr) * 32 + kc;

#define STAGE_S(buf, k0) do { \
    gload16(gA + (k0), As + (buf) * 4096 + ldsOff); \
    gload16(gA + (size_t)16 * lda + (k0), As + (buf) * 4096 + ldsOff + 16 * 32); \
    gload16(gB + (k0), Bs + (buf) * 4096 + ldsOff); \
    gload16(gB + (size_t)16 * K + (k0), Bs + (buf) * 4096 + ldsOff + 16 * 32); } while (0)

  GEMM_PIPE_LOOP(STAGE_S)
#undef STAGE_S

  int crow = (l >> 4) * 4;
  int ccol = l & 15;
  #pragma unroll
  for (int j = 0; j < 4; ++j) {
    int col = n0 + wc * 64 + j * 16 + ccol;
    int colr = col;
    if (REMAP) {
      int h = col / 192, r3 = col % 192;
      colr = (r3 / 64) * 2560 + h * 64 + (r3 & 63);
    }
    float bv = (EPI == 2) ? bias[col] : 0.f;
    #pragma unroll
    for (int i = 0; i < 4; ++i) {
      #pragma unroll
      for (int q = 0; q < 4; ++q) {
        int row = m0 + wr * 64 + i * 16 + crow + q;
        float v = acc[i][j][q];
        if constexpr (EPI == 2) v = 1.f / (1.f + expf(v + bv));
        C1[(size_t)row * ldc + colr] = f2bf(v);
      }
    }
  }
}

// ===============================================================
// 256^2 8-phase MFMA GEMM (T2 swizzle + T3/T4 counted vmcnt + T5).
// 512 thr = 8 waves (2M x 4N); per-wave 128x64 out (acc[8][4]).
// BK=64 = 2 ks-halves of [256 rows][32 k] per op; LDS 128 KB.
// Stage: 1 half (2 gloads/thr) per phase; lead 4 halves -> vmcnt(8)
// before close barrier of even phases; swizzle slot^= (row>>1)&3
// via inverse-swizzled global source + swizzled ds_read.
// MODE 0: xproj (REMAP, plain epi). MODE 1: big4 (which select,
// sigmoid for which<2).
// K fixed = 2560 (40 tiles, 20 iters, last peeled).
// ===============================================================
template<int MODE>
__global__ __launch_bounds__(512) void gemm256(
    const u16* __restrict__ A,
    const u16* __restrict__ W0, const u16* __restrict__ W1,
    const u16* __restrict__ W2, const u16* __restrict__ W3,
    u16* __restrict__ C0, u16* __restrict__ C1b,
    u16* __restrict__ C2, u16* __restrict__ C3) {
  const int K = 2560;
  __shared__ u16 As[32768];   // [2 buf][2 ks][256][32]
  __shared__ u16 Bs[32768];
  int tid = threadIdx.x;
  int wid = tid >> 6, l = tid & 63;
  int wr = wid >> 2, wc = wid & 3;
  int m0 = blockIdx.y * 256;
  int n0g = blockIdx.x * 256;
  int which = (MODE == 1) ? (n0g / 2560) : 0;
  int n0 = (MODE == 1) ? (n0g - which * 2560) : n0g;
  const u16* Wsel = (MODE == 0) ? W0 :
                    ((which == 0) ? W0 : (which == 1) ? W1 : (which == 2) ? W2 : W3);
  u16* Csel = (MODE == 0) ? C0 :
              ((which == 0) ? C0 : (which == 1) ? C1b : (which == 2) ? C2 : C3);

  f32x4 acc[8][4];
  #pragma unroll
  for (int i = 0; i < 8; ++i)
    #pragma unroll
    for (int j = 0; j < 4; ++j)
      acc[i][j] = (f32x4){0.f, 0.f, 0.f, 0.f};

  // staging addresses: row = base + q*128 + (tid>>2); physical slot tid&3
  // holds logical k-slot (tid&3)^((tid>>3)&3)  [involution, row>>1&3]
  int swzc = (((tid & 3) ^ ((tid >> 3) & 3)) * 8);
  const u16* sA = A    + (size_t)(m0 + (tid >> 2)) * K + swzc;
  const u16* sB = Wsel + (size_t)(n0 + (tid >> 2)) * K + swzc;

  // read addresses: lane l -> fr=l&15 (row), u=l>>4 (logical slot)
  int fr = l & 15, u = l >> 4;
  int rsw = ((u ^ ((fr >> 1) & 3)) * 8);
  const u16* rA0 = As + (size_t)(wr * 128 + fr) * 32 + rsw;
  const u16* rB0 = Bs + (size_t)(wc * 64 + fr) * 32 + rsw;

#define STGA(buf, ks, T) do { \
    const u16* _s = sA + (size_t)(T) * 64 + (ks) * 32; \
    u16* _d = As + (buf) * 16384 + (ks) * 8192 + tid * 8; \
    gload16(_s, _d); gload16(_s + (size_t)128 * K, _d + 4096); } while (0)
#define STGB(buf, ks, T) do { \
    const u16* _s = sB + (size_t)(T) * 64 + (ks) * 32; \
    u16* _d = Bs + (buf) * 16384 + (ks) * 8192 + tid * 8; \
    gload16(_s, _d); gload16(_s + (size_t)128 * K, _d + 4096); } while (0)
#define RDA(i, buf, ks) (*(const bf16x8*)(rA0 + (buf) * 16384 + (ks) * 8192 + (i) * 512))
#define RDB(j, buf, ks) (*(const bf16x8*)(rB0 + (buf) * 16384 + (ks) * 8192 + (j) * 512))
#define CLOSEB do { \
    __builtin_amdgcn_sched_barrier(0); \
    __builtin_amdgcn_s_barrier(); \
    __builtin_amdgcn_sched_barrier(0); } while (0)
#define VM8 asm volatile("s_waitcnt vmcnt(8)" ::: "memory")
#define VM4 asm volatile("s_waitcnt vmcnt(4)" ::: "memory")
#define VM0 asm volatile("s_waitcnt vmcnt(0)" ::: "memory")
#define MFMA16(mh) do { \
    acc[(mh)*4+0][0] = __builtin_amdgcn_mfma_f32_16x16x32_bf16(a0, b0, acc[(mh)*4+0][0], 0, 0, 0); \
    acc[(mh)*4+0][1] = __builtin_amdgcn_mfma_f32_16x16x32_bf16(a0, b1, acc[(mh)*4+0][1], 0, 0, 0); \
    acc[(mh)*4+0][2] = __builtin_amdgcn_mfma_f32_16x16x32_bf16(a0, b2, acc[(mh)*4+0][2], 0, 0, 0); \
    acc[(mh)*4+0][3] = __builtin_amdgcn_mfma_f32_16x16x32_bf16(a0, b3, acc[(mh)*4+0][3], 0, 0, 0); \
    acc[(mh)*4+1][0] = __builtin_amdgcn_mfma_f32_16x16x32_bf16(a1, b0, acc[(mh)*4+1][0], 0, 0, 0); \
    acc[(mh)*4+1][1] = __builtin_amdgcn_mfma_f32_16x16x32_bf16(a1, b1, acc[(mh)*4+1][1], 0, 0, 0); \
    acc[(mh)*4+1][2] = __builtin_amdgcn_mfma_f32_16x16x32_bf16(a1, b2, acc[(mh)*4+1][2], 0, 0, 0); \
    acc[(mh)*4+1][3] = __builtin_amdgcn_mfma_f32_16x16x32_bf16(a1, b3, acc[(mh)*4+1][3], 0, 0, 0); \
    acc[(mh)*4+2][0] = __builtin_amdgcn_mfma_f32_16x16x32_bf16(a2, b0, acc[(mh)*4+2][0], 0, 0, 0); \
    acc[(mh)*4+2][1] = __builtin_amdgcn_mfma_f32_16x16x32_bf16(a2, b1, acc[(mh)*4+2][1], 0, 0, 0); \
    acc[(mh)*4+2][2] = __builtin_amdgcn_mfma_f32_16x16x32_bf16(a2, b2, acc[(mh)*4+2][2], 0, 0, 0); \
    acc[(mh)*4+2][3] = __builtin_amdgcn_mfma_f32_16x16x32_bf16(a2, b3, acc[(mh)*4+2][3], 0, 0, 0); \
    acc[(mh)*4+3][0] = __builtin_amdgcn_mfma_f32_16x16x32_bf16(a3, b0, acc[(mh)*4+3][0], 0, 0, 0); \
    acc[(mh)*4+3][1] = __builtin_amdgcn_mfma_f32_16x16x32_bf16(a3, b1, acc[(mh)*4+3][1], 0, 0, 0); \
    acc[(mh)*4+3][2] = __builtin_amdgcn_mfma_f32_16x16x32_bf16(a3, b2, acc[(mh)*4+3][2], 0, 0, 0); \
    acc[(mh)*4+3][3] = __builtin_amdgcn_mfma_f32_16x16x32_bf16(a3, b3, acc[(mh)*4+3][3], 0, 0, 0); } while (0)
#define PHASE(buf, ks, mh, RB, STG_STMT) do { \
    if (RB) { b0 = RDB(0, buf, ks); b1 = RDB(1, buf, ks); \
              b2 = RDB(2, buf, ks); b3 = RDB(3, buf, ks); } \
    a0 = RDA((mh)*4+0, buf, ks); a1 = RDA((mh)*4+1, buf, ks); \
    a2 = RDA((mh)*4+2, buf, ks); a3 = RDA((mh)*4+3, buf, ks); \
    STG_STMT; \
    __builtin_amdgcn_sched_barrier(0); \
    __builtin_amdgcn_s_barrier(); \
    __builtin_amdgcn_sched_barrier(0); \
    __builtin_amdgcn_s_setprio(1); \
    MFMA16(mh); \
    __builtin_amdgcn_s_setprio(0); } while (0)

  bf16x8 a0, a1, a2, a3, b0, b1, b2, b3;

  // prologue: tile0.K0(A,B), tile0.K1(A,B), tile1.K0(A,B)
  STGA(0, 0, 0); STGB(0, 0, 0);
  STGA(0, 1, 0); STGB(0, 1, 0);
  STGA(1, 0, 1); STGB(1, 0, 1);
  VM8; CLOSEB;

  const int nIter = 20;   // K/128
  for (int it = 0; it < nIter - 1; ++it) {
    int T1 = 2 * it + 1, T2 = 2 * it + 2, T3 = 2 * it + 3;
    PHASE(0, 0, 0, 1, STGA(1, 1, T1));            CLOSEB;   // p1
    PHASE(0, 0, 1, 0, STGB(1, 1, T1));  VM8;      CLOSEB;   // p2
    PHASE(0, 1, 0, 1, STGA(0, 0, T2));            CLOSEB;   // p3
    PHASE(0, 1, 1, 0, STGB(0, 0, T2));  VM8;      CLOSEB;   // p4
    PHASE(1, 0, 0, 1, STGA(0, 1, T2));            CLOSEB;   // p5
    PHASE(1, 0, 1, 0, STGB(0, 1, T2));  VM8;      CLOSEB;   // p6
    PHASE(1, 1, 0, 1, STGA(1, 0, T3));            CLOSEB;   // p7
    PHASE(1, 1, 1, 0, STGB(1, 0, T3));  VM8;      CLOSEB;   // p8
  }
  {
    int T1 = 2 * (nIter - 1) + 1;                 // = 39
    PHASE(0, 0, 0, 1, STGA(1, 1, T1));            CLOSEB;   // p1
    PHASE(0, 0, 1, 0, STGB(1, 1, T1));  VM8;      CLOSEB;   // p2
    PHASE(0, 1, 0, 1, (void)0);                   CLOSEB;   // p3
    PHASE(0, 1, 1, 0, (void)0);         VM4;      CLOSEB;   // p4
    PHASE(1, 0, 0, 1, (void)0);                   CLOSEB;   // p5
    PHASE(1, 0, 1, 0, (void)0);         VM0;      CLOSEB;   // p6
    PHASE(1, 1, 0, 1, (void)0);                   CLOSEB;   // p7
    PHASE(1, 1, 1, 0, (void)0);                   CLOSEB;   // p8
  }
#undef STGA
#undef STGB
#undef RDA
#undef RDB
#undef CLOSEB
#undef VM8
#undef VM4
#undef VM0
#undef MFMA16
#undef PHASE

  // epilogue: C/D map col = lane&15, row = (lane>>4)*4 + q
  bool sig = (MODE == 1) && (which < 2);
  int ldc = (MODE == 0) ? NPROJ : DIM;
  #pragma unroll
  for (int j = 0; j < 4; ++j) {
    int col = n0 + wc * 64 + j * 16 + fr;
    int colr = col;
    if (MODE == 0) {
      int h = col / 192, r3 = col % 192;
      colr = (r3 / 64) * 2560 + h * 64 + (r3 & 63);
    }
    #pragma unroll
    for (int i = 0; i < 8; ++i) {
      #pragma unroll
      for (int q = 0; q < 4; ++q) {
        int row = m0 + wr * 128 + i * 16 + u * 4 + q;
        float v = acc[i][j][q];
        if (sig) v = 1.f / (1.f + expf(-v));
        Csel[(size_t)row * ldc + colr] = f2bf(v);
      }
    }
  }
}

// ===============================================================
// Chunked parallel scan (round-10 structure, unchanged).
// ===============================================================
__global__ __launch_bounds__(128) void scan_local_kernel(
    const u16* __restrict__ wdec, const u16* __restrict__ proj,
    const u16* __restrict__ kb, const u16* __restrict__ vb,
    u16* __restrict__ yout,
    float* __restrict__ Sbuf, float* __restrict__ Pbuf) {
  int bx = blockIdx.x;
  int bh = bx / NC, c = bx % NC;
  int b = bh / NH, h = bh % NH;
  int wv = threadIdx.x >> 6;
  int lane = threadIdx.x & 63;
  int sg = lane >> 3, dd = lane & 7;
  int s0 = sg * 8;
  int d0 = wv * 32 + dd * 4;
  int l0 = c * CH;

  const u16* fw = wdec + ((size_t)(b * LL + l0)) * DIM + h * 64 + s0;
  const u16* fB = proj + ((size_t)(b * LL + l0)) * NPROJ + 2560 + h * 64 + s0;
  const u16* fC = fB + 2560;
  const u16* fk = kb + ((size_t)(b * LL + l0)) * DIM + h * 64 + d0;
  const u16* fv = vb + ((size_t)(b * LL + l0)) * DIM + h * 64 + d0;
  u16* py = yout + ((size_t)(b * LL + l0)) * NPROJ + h * 64 + d0;

  float st[8][4];
  float pc[8];
  #pragma unroll
  for (int i = 0; i < 8; ++i) {
    pc[i] = 1.f;
    #pragma unroll
    for (int j = 0; j < 4; ++j) st[i][j] = 0.f;
  }

#define P1_DECL(n) uint4 wS##n, BS##n, CS##n; uint2 kS##n, vS##n
#define P1_LOAD(n) do { \
    wS##n = *(const uint4*)fw; BS##n = *(const uint4*)fB; \
    CS##n = *(const uint4*)fC; kS##n = *(const uint2*)fk; \
    vS##n = *(const uint2*)fv; \
    fw += DIM; fB += NPROJ; fC += NPROJ; fk += DIM; fv += DIM; } while (0)
#define P1_PROC(n) do { \
    float wv8[8], Bv[8], Cv[8], kv4[4], pr[4]; \
    wv8[0]=bflo(wS##n.x); wv8[1]=bfhi(wS##n.x); wv8[2]=bflo(wS##n.y); wv8[3]=bfhi(wS##n.y); \
    wv8[4]=bflo(wS##n.z); wv8[5]=bfhi(wS##n.z); wv8[6]=bflo(wS##n.w); wv8[7]=bfhi(wS##n.w); \
    Bv[0]=bflo(BS##n.x); Bv[1]=bfhi(BS##n.x); Bv[2]=bflo(BS##n.y); Bv[3]=bfhi(BS##n.y); \
    Bv[4]=bflo(BS##n.z); Bv[5]=bfhi(BS##n.z); Bv[6]=bflo(BS##n.w); Bv[7]=bfhi(BS##n.w); \
    Cv[0]=bflo(CS##n.x); Cv[1]=bfhi(CS##n.x); Cv[2]=bflo(CS##n.y); Cv[3]=bfhi(CS##n.y); \
    Cv[4]=bflo(CS##n.z); Cv[5]=bfhi(CS##n.z); Cv[6]=bflo(CS##n.w); Cv[7]=bfhi(CS##n.w); \
    kv4[0]=bflo(kS##n.x)*bflo(vS##n.x); kv4[1]=bfhi(kS##n.x)*bfhi(vS##n.x); \
    kv4[2]=bflo(kS##n.y)*bflo(vS##n.y); kv4[3]=bfhi(kS##n.y)*bfhi(vS##n.y); \
    pr[0]=0.f; pr[1]=0.f; pr[2]=0.f; pr[3]=0.f; \
    _Pragma("unroll") \
    for (int i = 0; i < 8; ++i) { \
      pc[i] *= wv8[i]; \
      _Pragma("unroll") \
      for (int j = 0; j < 4; ++j) { \
        st[i][j] = fmaf(wv8[i], st[i][j], Bv[i] * kv4[j]); \
        pr[j] = fmaf(st[i][j], Cv[i], pr[j]); } } \
    _Pragma("unroll") \
    for (int j = 0; j < 4; ++j) { \
      pr[j] += __shfl_xor(pr[j], 8, 64); \
      pr[j] += __shfl_xor(pr[j], 16, 64); \
      pr[j] += __shfl_xor(pr[j], 32, 64); } \
    if (lane < 8) { \
      uint2 ov; \
      ov.x = (unsigned)f2bf(pr[0]) | ((unsigned)f2bf(pr[1]) << 16); \
      ov.y = (unsigned)f2bf(pr[2]) | ((unsigned)f2bf(pr[3]) << 16); \
      *(uint2*)py = ov; } \
    py += NPROJ; } while (0)

  P1_DECL(0); P1_DECL(1); P1_DECL(2); P1_DECL(3);
  P1_LOAD(0); P1_LOAD(1); P1_LOAD(2); P1_LOAD(3);
  for (int l = 0; l < CH; l += 4) {
    P1_PROC(0); P1_LOAD(0);
    P1_PROC(1); P1_LOAD(1);
    P1_PROC(2); P1_LOAD(2);
    P1_PROC(3); P1_LOAD(3);
  }
#undef P1_DECL
#undef P1_LOAD
#undef P1_PROC

  float* Sp = Sbuf + (((size_t)c * BH + bh) * 64 + s0) * 64 + d0;
  #pragma unroll
  for (int i = 0; i < 8; ++i) {
    float4 v; v.x = st[i][0]; v.y = st[i][1]; v.z = st[i][2]; v.w = st[i][3];
    *(float4*)(Sp + (size_t)i * 64) = v;
  }
  if (wv == 0 && dd == 0) {
    #pragma unroll
    for (int i = 0; i < 8; ++i)
      Pbuf[((size_t)c * BH + bh) * 64 + s0 + i] = pc[i];
  }
}

// ---------------------------------------------------------------
__global__ __launch_bounds__(256) void scan_combine_kernel(
    float* __restrict__ Sbuf, const float* __restrict__ Pbuf,
    float* __restrict__ fstate) {
  int bh = blockIdx.x;
  int t = threadIdx.x;
  int s = t >> 2, j0 = (t & 3) * 16;
  float stin[16];
  #pragma unroll
  for (int k = 0; k < 16; ++k) stin[k] = 0.f;
  for (int c = 0; c < NC; ++c) {
    float* Sp = Sbuf + (((size_t)c * BH + bh) * 64 + s) * 64 + j0;
    float Pc = Pbuf[((size_t)c * BH + bh) * 64 + s];
    #pragma unroll
    for (int q = 0; q < 4; ++q) {
      float4 a = *(const float4*)(Sp + q * 4);
      float4 cur;
      cur.x = stin[q*4+0]; cur.y = stin[q*4+1];
      cur.z = stin[q*4+2]; cur.w = stin[q*4+3];
      *(float4*)(Sp + q * 4) = cur;           // S slot now holds st_in for chunk c
      stin[q*4+0] = a.x + Pc * stin[q*4+0];
      stin[q*4+1] = a.y + Pc * stin[q*4+1];
      stin[q*4+2] = a.z + Pc * stin[q*4+2];
      stin[q*4+3] = a.w + Pc * stin[q*4+3];
    }
  }
  float* fp = fstate + ((size_t)bh * 64 + s) * 64 + j0;
  #pragma unroll
  for (int q = 0; q < 4; ++q) {
    float4 v;
    v.x = stin[q*4+0]; v.y = stin[q*4+1];
    v.z = stin[q*4+2]; v.w = stin[q*4+3];
    *(float4*)(fp + q * 4) = v;
  }
}

// ---------------------------------------------------------------
// Phase 3 + fused gate: y_final = r * (y_local + C.(cumw*st_in)) * g
// ---------------------------------------------------------------
__global__ __launch_bounds__(128) void scan_correct_kernel(
    const u16* __restrict__ wdec, const u16* __restrict__ proj,
    const u16* __restrict__ rb, const u16* __restrict__ gb,
    const float* __restrict__ Sbuf, u16* __restrict__ yio) {
  int bx = blockIdx.x;
  int bh = bx / NC, c = bx % NC;
  int b = bh / NH, h = bh % NH;
  int wv = threadIdx.x >> 6;
  int lane = threadIdx.x & 63;
  int sg = lane >> 3, dd = lane & 7;
  int s0 = sg * 8;
  int d0 = wv * 32 + dd * 4;
  int l0 = c * CH;

  const float* Sp = Sbuf + (((size_t)c * BH + bh) * 64 + s0) * 64 + d0;
  float stin[8][4];
  #pragma unroll
  for (int i = 0; i < 8; ++i) {
    float4 v = *(const float4*)(Sp + (size_t)i * 64);
    stin[i][0] = v.x; stin[i][1] = v.y; stin[i][2] = v.z; stin[i][3] = v.w;
  }

  const u16* fw = wdec + ((size_t)(b * LL + l0)) * DIM + h * 64 + s0;
  const u16* fC = proj + ((size_t)(b * LL + l0)) * NPROJ + 5120 + h * 64 + s0;
  const u16* fy = yio  + ((size_t)(b * LL + l0)) * NPROJ + h * 64 + d0;
  const u16* fr2 = rb + ((size_t)(b * LL + l0)) * DIM + h * 64 + d0;
  const u16* fg2 = gb + ((size_t)(b * LL + l0)) * DIM + h * 64 + d0;
  u16* py = yio + ((size_t)(b * LL + l0)) * NPROJ + h * 64 + d0;

  float pc[8];
  #pragma unroll
  for (int i = 0; i < 8; ++i) pc[i] = 1.f;

#define P3_DECL(n) uint4 wT##n, CT##n; uint2 yT##n, rT##n, gT##n
#define P3_LOAD(n) do { \
    wT##n = *(const uint4*)fw; CT##n = *(const uint4*)fC; \
    yT##n = *(const uint2*)fy; rT##n = *(const uint2*)fr2; gT##n = *(const uint2*)fg2; \
    fw += DIM; fC += NPROJ; fy += NPROJ; fr2 += DIM; fg2 += DIM; } while (0)
#define P3_PROC(n) do { \
    float wv8[8], Cv[8], ac[8], pr[4]; \
    wv8[0]=bflo(wT##n.x); wv8[1]=bfhi(wT##n.x); wv8[2]=bflo(wT##n.y); wv8[3]=bfhi(wT##n.y); \
    wv8[4]=bflo(wT##n.z); wv8[5]=bfhi(wT##n.z); wv8[6]=bflo(wT##n.w); wv8[7]=bfhi(wT##n.w); \
    Cv[0]=bflo(CT##n.x); Cv[1]=bfhi(CT##n.x); Cv[2]=bflo(CT##n.y); Cv[3]=bfhi(CT##n.y); \
    Cv[4]=bflo(CT##n.z); Cv[5]=bfhi(CT##n.z); Cv[6]=bflo(CT##n.w); Cv[7]=bfhi(CT##n.w); \
    pr[0]=0.f; pr[1]=0.f; pr[2]=0.f; pr[3]=0.f; \
    _Pragma("unroll") \
    for (int i = 0; i < 8; ++i) { \
      pc[i] *= wv8[i]; ac[i] = pc[i] * Cv[i]; \
      _Pragma("unroll") \
      for (int j = 0; j < 4; ++j) pr[j] = fmaf(ac[i], stin[i][j], pr[j]); } \
    _Pragma("unroll") \
    for (int j = 0; j < 4; ++j) { \
      pr[j] += __shfl_xor(pr[j], 8, 64); \
      pr[j] += __shfl_xor(pr[j], 16, 64); \
      pr[j] += __shfl_xor(pr[j], 32, 64); } \
    if (lane < 8) { \
      float y0 = (bflo(yT##n.x) + pr[0]) * bflo(rT##n.x) * bflo(gT##n.x); \
      float y1 = (bfhi(yT##n.x) + pr[1]) * bfhi(rT##n.x) * bfhi(gT##n.x); \
      float y2 = (bflo(yT##n.y) + pr[2]) * bflo(rT##n.y) * bflo(gT##n.y); \
      float y3 = (bfhi(yT##n.y) + pr[3]) * bfhi(rT##n.y) * bfhi(gT##n.y); \
      uint2 ov; \
      ov.x = (unsigned)f2bf(y0) | ((unsigned)f2bf(y1) << 16); \
      ov.y = (unsigned)f2bf(y2) | ((unsigned)f2bf(y3) << 16); \
      *(uint2*)py = ov; } \
    py += NPROJ; } while (0)

  P3_DECL(0); P3_DECL(1); P3_DECL(2); P3_DECL(3);
  P3_LOAD(0); P3_LOAD(1); P3_LOAD(2); P3_LOAD(3);
  for (int l = 0; l < CH; l += 4) {
    P3_PROC(0); P3_LOAD(0);
    P3_PROC(1); P3_LOAD(1);
    P3_PROC(2); P3_LOAD(2);
    P3_PROC(3); P3_LOAD(3);
  }
#undef P3_DECL
#undef P3_LOAD
#undef P3_PROC
}

// ---------------------------------------------------------------
extern "C" void kernel_launch(void* const* d_in, const int* in_sizes, int n_in,
                              void* d_out, int out_size, void* d_ws, size_t ws_size,
                              hipStream_t stream) {
  const float* x    = (const float*)d_in[0];
  const float* W_r  = (const float*)d_in[1];
  const float* W_k  = (const float*)d_in[2];
  const float* W_v  = (const float*)d_in[3];
  const float* W_g  = (const float*)d_in[4];
  const float* W_xp = (const float*)d_in[5];
  const float* W_dt = (const float*)d_in[6];
  const float* b_dt = (const float*)d_in[7];
  const float* cw   = (const float*)d_in[8];
  const float* ln1g = (const float*)d_in[9];
  const float* ln1b = (const float*)d_in[10];
  const float* ln2g = (const float*)d_in[11];
  const float* ln2b = (const float*)d_in[12];
  const float* W_o  = (const float*)d_in[13];

  float* out    = (float*)d_out;
  float* fstate = out + (size_t)MTOT * DIM;

  const size_t nBL = (size_t)MTOT * DIM;
  const size_t nPJ = (size_t)MTOT * NPROJ;
  const size_t nWX = (size_t)NPROJ * DIM;
  const size_t nDD = (size_t)DIM * DIM;
  const size_t needed = (nBL * 5 + nPJ + nWX) * sizeof(u16);  // ~207 MB
  if (ws_size < needed) {
    fill_kernel<<<(out_size + 255) / 256, 256, 0, stream>>>(out, out_size, 1234.5f);
    return;
  }

  u16* wsp  = (u16*)d_ws;
  u16* x1   = wsp;
  u16* proj = x1 + nBL;
  u16* wdec = proj + nPJ;       // reused for y2 after recurrence
  u16* rb   = wdec + nBL;
  u16* gb   = rb + nBL;
  u16* kvb  = gb + nBL;         // holds k
  u16* wscr = kvb + nBL;        // weight scratch (nWX elems); scan S/P live here
  float* Sbuf = (float*)wscr;                       // NC*BH*64*64 fp32 = 21 MB
  float* Pbuf = Sbuf + (size_t)NC * BH * 64 * 64;   // NC*BH*64 fp32 = 0.3 MB

  // v output and Wv(bf16) live in d_out's `out` region (dead until ln2;
  // fstate region untouched: 5.24M+3.28M < 10.49M floats)
  u16* vscr = (u16*)d_out;        // nBL u16 = 21 MB
  u16* wvb  = vscr + nBL;         // nDD u16 = 13.1 MB

  const int nDD4 = (int)(nDD / 4);

  // 1. conv + LN1 -> x1 (bf16)
  conv_ln1_kernel<<<MTOT, 256, 0, stream>>>(x, cw, ln1g, ln1b, x1);

  // 2. proj = x1 @ W_xproj^T  (REMAP columns to [dt|B|C]) -- 256^2 8-phase
  cvt_kernel<<<2048, 256, 0, stream>>>(W_xp, wscr, NPROJ * DIM / 4);
  gemm256<0><<<dim3(NPROJ/256, MTOT/256), 512, 0, stream>>>(
      x1, wscr, nullptr, nullptr, nullptr, proj, nullptr, nullptr, nullptr);

  // 3. w = exp(-softplus(proj_dt @ W_dt^T + b_dt)) -- 128^2 core
  cvt_kernel<<<2048, 256, 0, stream>>>(W_dt, wscr, nDD4);
  gemm_mfma<2,false><<<dim3(DIM/128, MTOT/128), 256, 0, stream>>>(proj, NPROJ, wscr, b_dt, wdec, DIM, DIM);

  // 4. batched r|g|k|v GEMM -- 256^2 8-phase (N=10240, 640 blocks)
  Cvt4Args ca;
  ca.s0 = W_r; ca.s1 = W_g; ca.s2 = W_k; ca.s3 = W_v;
  ca.d0 = wscr; ca.d1 = wscr + nDD; ca.d2 = wscr + 2 * nDD; ca.d3 = wvb;
  cvt4_kernel<<<2048, 256, 0, stream>>>(ca, nDD4);
  gemm256<1><<<dim3(4 * DIM / 256, MTOT / 256), 512, 0, stream>>>(
      x1, wscr, wscr + nDD, wscr + 2 * nDD, wvb, rb, gb, kvb, vscr);

  // 5. chunked scan: local (kv=k*v inline) -> combine(fstate) -> correct(+gate)
  scan_local_kernel<<<BH * NC, 128, 0, stream>>>(wdec, proj, kvb, vscr, proj, Sbuf, Pbuf);
  scan_combine_kernel<<<BH, 256, 0, stream>>>(Sbuf, Pbuf, fstate);
  scan_correct_kernel<<<BH * NC, 128, 0, stream>>>(wdec, proj, rb, gb, Sbuf, proj);

  // 6. y2 = out_inner @ W_out^T -> wdec (reuse); A = proj y-region (lda=NPROJ)
  cvt_kernel<<<2048, 256, 0, stream>>>(W_o, wscr, nDD4);
  gemm_mfma<0,false><<<dim3(DIM/128, MTOT/128), 256, 0, stream>>>(proj, NPROJ, wscr, nullptr, wdec, DIM, DIM);

  // 7. out = LN(x1 + y2) -> fp32
  ln2_kernel<<<MTOT, 256, 0, stream>>>(x1, wdec, ln2g, ln2b, out);
}

// Round 13
// 891.742 us; speedup vs baseline: 1.4578x; 1.0045x over previous
//
#include <hip/hip_runtime.h>
#include <cstddef>
#include <cstdint>

#define DIM 2560
#define NH 40
#define HDD 64
#define SD 64
#define KC 4
#define BB 2
#define LL 2048
#define MTOT (BB*LL)      // 4096
#define NPROJ (NH*3*SD)   // 7680
#define NC 16             // scan chunks
#define CH (LL/NC)        // 128 steps per chunk
#define BH (BB*NH)        // 80

typedef unsigned short u16;
typedef __attribute__((ext_vector_type(8))) short bf16x8;
typedef __attribute__((ext_vector_type(4))) float f32x4;

__device__ inline float bf2f(u16 u) { return __uint_as_float(((unsigned)u) << 16); }
__device__ inline float bflo(unsigned u) { return __uint_as_float(u << 16); }
__device__ inline float bfhi(unsigned u) { return __uint_as_float(u & 0xffff0000u); }
__device__ inline u16 f2bf(float f) {
  unsigned x = __float_as_uint(f);
  unsigned r = (x + 0x7fffu + ((x >> 16) & 1u)) >> 16;   // RNE
  return (u16)r;
}

__device__ inline void gload16(const void* g, void* lds) {
  __builtin_amdgcn_global_load_lds(
      (const __attribute__((address_space(1))) void*)g,
      (__attribute__((address_space(3))) void*)(uint32_t)(size_t)lds,
      16, 0, 0);
}

// ---------------------------------------------------------------
__global__ __launch_bounds__(256) void cvt_kernel(
    const float* __restrict__ src, u16* __restrict__ dst, int n4) {
  int i = blockIdx.x * 256 + threadIdx.x;
  int stride = gridDim.x * 256;
  for (; i < n4; i += stride) {
    float4 v = *(const float4*)(src + (size_t)i * 4);
    ushort4 o;
    o.x = f2bf(v.x); o.y = f2bf(v.y); o.z = f2bf(v.z); o.w = f2bf(v.w);
    *(ushort4*)(dst + (size_t)i * 4) = o;
  }
}

// ---------------------------------------------------------------
struct Cvt4Args { const float* s0; const float* s1; const float* s2; const float* s3;
                  u16* d0; u16* d1; u16* d2; u16* d3; };
__global__ __launch_bounds__(256) void cvt4_kernel(Cvt4Args a, int n4each) {
  int i = blockIdx.x * 256 + threadIdx.x;
  int stride = gridDim.x * 256;
  int total = 4 * n4each;
  for (; i < total; i += stride) {
    int which = i / n4each;
    int loc = i - which * n4each;
    const float* s = (which == 0) ? a.s0 : (which == 1) ? a.s1 : (which == 2) ? a.s2 : a.s3;
    u16* d = (which == 0) ? a.d0 : (which == 1) ? a.d1 : (which == 2) ? a.d2 : a.d3;
    float4 v = *(const float4*)(s + (size_t)loc * 4);
    ushort4 o;
    o.x = f2bf(v.x); o.y = f2bf(v.y); o.z = f2bf(v.z); o.w = f2bf(v.w);
    *(ushort4*)(d + (size_t)loc * 4) = o;
  }
}

// ---------------------------------------------------------------
__global__ __launch_bounds__(256) void fill_kernel(float* p, int n, float v) {
  int i = blockIdx.x * 256 + threadIdx.x;
  if (i < n) p[i] = v;
}

// ---------------------------------------------------------------
__device__ inline void block_reduce2(float& sum, float& sq, float* red) {
  #pragma unroll
  for (int off = 32; off; off >>= 1) {
    sum += __shfl_down(sum, off, 64);
    sq  += __shfl_down(sq,  off, 64);
  }
  int wid = threadIdx.x >> 6, lane = threadIdx.x & 63;
  if (lane == 0) { red[wid*2] = sum; red[wid*2+1] = sq; }
  __syncthreads();
  sum = red[0] + red[2] + red[4] + red[6];
  sq  = red[1] + red[3] + red[5] + red[7];
}

// ---------------------------------------------------------------
// conv (causal depthwise, K=4) + residual + LayerNorm1 -> bf16
// VECTORIZED: float4 loads for x/taps/cw/g/b, ushort4 stores.
// thread t handles float4 chunks {t, t+256, t+512 (t<128)}.
// ---------------------------------------------------------------
__global__ __launch_bounds__(256) void conv_ln1_kernel(
    const float* __restrict__ x, const float* __restrict__ cw,
    const float* __restrict__ g1, const float* __restrict__ b1,
    u16* __restrict__ x1) {
  __shared__ float red[8];
  int bl = blockIdx.x;
  int l  = bl & (LL - 1);
  int t  = threadIdx.x;
  const float* xr = x + (size_t)bl * DIM;
  bool m3 = (l >= 3), m2 = (l >= 2), m1 = (l >= 1);
  bool has3 = (t < 128);
  float4 v0, v1, v2;
  float sum = 0.f, sq = 0.f;

#define CONV_CHUNK(VOUT, D0) do { \
    int d0 = (D0); \
    float4 a  = *(const float4*)(xr + d0); \
    float4 c0 = *(const float4*)(cw + (size_t)d0 * 4); \
    float4 c1 = *(const float4*)(cw + (size_t)d0 * 4 + 4); \
    float4 c2 = *(const float4*)(cw + (size_t)d0 * 4 + 8); \
    float4 c3 = *(const float4*)(cw + (size_t)d0 * 4 + 12); \
    float4 acc; \
    acc.x = fmaf(a.x, c0.w, a.x); acc.y = fmaf(a.y, c1.w, a.y); \
    acc.z = fmaf(a.z, c2.w, a.z); acc.w = fmaf(a.w, c3.w, a.w); \
    if (m3) { float4 p = *(const float4*)(xr - 3 * DIM + d0); \
      acc.x = fmaf(p.x, c0.x, acc.x); acc.y = fmaf(p.y, c1.x, acc.y); \
      acc.z = fmaf(p.z, c2.x, acc.z); acc.w = fmaf(p.w, c3.x, acc.w); } \
    if (m2) { float4 p = *(const float4*)(xr - 2 * DIM + d0); \
      acc.x = fmaf(p.x, c0.y, acc.x); acc.y = fmaf(p.y, c1.y, acc.y); \
      acc.z = fmaf(p.z, c2.y, acc.z); acc.w = fmaf(p.w, c3.y, acc.w); } \
    if (m1) { float4 p = *(const float4*)(xr - 1 * DIM + d0); \
      acc.x = fmaf(p.x, c0.z, acc.x); acc.y = fmaf(p.y, c1.z, acc.y); \
      acc.z = fmaf(p.z, c2.z, acc.z); acc.w = fmaf(p.w, c3.z, acc.w); } \
    VOUT = acc; \
    sum += acc.x + acc.y + acc.z + acc.w; \
    sq  += acc.x*acc.x + acc.y*acc.y + acc.z*acc.z + acc.w*acc.w; } while (0)

  CONV_CHUNK(v0, t * 4);
  CONV_CHUNK(v1, (t + 256) * 4);
  if (has3) CONV_CHUNK(v2, (t + 512) * 4);
#undef CONV_CHUNK

  block_reduce2(sum, sq, red);
  float mean = sum * (1.f / DIM);
  float var  = sq * (1.f / DIM) - mean * mean;
  float rstd = rsqrtf(var + 1e-5f);
  u16* orow = x1 + (size_t)bl * DIM;

#define CONV_STORE(V, D0) do { \
    int d0 = (D0); \
    float4 gg = *(const float4*)(g1 + d0); \
    float4 bb = *(const float4*)(b1 + d0); \
    ushort4 o; \
    o.x = f2bf((V.x - mean) * rstd * gg.x + bb.x); \
    o.y = f2bf((V.y - mean) * rstd * gg.y + bb.y); \
    o.z = f2bf((V.z - mean) * rstd * gg.z + bb.z); \
    o.w = f2bf((V.w - mean) * rstd * gg.w + bb.w); \
    *(ushort4*)(orow + d0) = o; } while (0)

  CONV_STORE(v0, t * 4);
  CONV_STORE(v1, (t + 256) * 4);
  if (has3) CONV_STORE(v2, (t + 512) * 4);
#undef CONV_STORE
}

// ---------------------------------------------------------------
// LN2: out = LN(x1 + y2), bf16 inputs -> fp32 out
// VECTORIZED: uint4 (8 bf16) loads, float4 stores.
// thread t handles 8-elem chunks {t, 256+t (t<64)}.
// ---------------------------------------------------------------
__global__ __launch_bounds__(256) void ln2_kernel(
    const u16* __restrict__ x1, const u16* __restrict__ y2,
    const float* __restrict__ g2, const float* __restrict__ b2,
    float* __restrict__ out) {
  __shared__ float red[8];
  int bl = blockIdx.x;
  int t  = threadIdx.x;
  const u16* ar = x1 + (size_t)bl * DIM;
  const u16* br = y2 + (size_t)bl * DIM;
  bool has2 = (t < 64);
  float f0[8], f1[8];
  float sum = 0.f, sq = 0.f;

#define LN2_CHUNK(F, D0) do { \
    int d0 = (D0); \
    uint4 xa = *(const uint4*)(ar + d0); \
    uint4 xb = *(const uint4*)(br + d0); \
    F[0] = bflo(xa.x) + bflo(xb.x); F[1] = bfhi(xa.x) + bfhi(xb.x); \
    F[2] = bflo(xa.y) + bflo(xb.y); F[3] = bfhi(xa.y) + bfhi(xb.y); \
    F[4] = bflo(xa.z) + bflo(xb.z); F[5] = bfhi(xa.z) + bfhi(xb.z); \
    F[6] = bflo(xa.w) + bflo(xb.w); F[7] = bfhi(xa.w) + bfhi(xb.w); \
    _Pragma("unroll") \
    for (int q = 0; q < 8; ++q) { sum += F[q]; sq += F[q] * F[q]; } } while (0)

  LN2_CHUNK(f0, t * 8);
  if (has2) LN2_CHUNK(f1, (256 + t) * 8);
#undef LN2_CHUNK

  block_reduce2(sum, sq, red);
  float mean = sum * (1.f / DIM);
  float var  = sq * (1.f / DIM) - mean * mean;
  float rstd = rsqrtf(var + 1e-5f);
  float* orow = out + (size_t)bl * DIM;

#define LN2_STORE(F, D0) do { \
    int d0 = (D0); \
    float4 ga = *(const float4*)(g2 + d0); \
    float4 gb = *(const float4*)(g2 + d0 + 4); \
    float4 ba = *(const float4*)(b2 + d0); \
    float4 bb = *(const float4*)(b2 + d0 + 4); \
    float4 o0, o1; \
    o0.x = (F[0] - mean) * rstd * ga.x + ba.x; \
    o0.y = (F[1] - mean) * rstd * ga.y + ba.y; \
    o0.z = (F[2] - mean) * rstd * ga.z + ba.z; \
    o0.w = (F[3] - mean) * rstd * ga.w + ba.w; \
    o1.x = (F[4] - mean) * rstd * gb.x + bb.x; \
    o1.y = (F[5] - mean) * rstd * gb.y + bb.y; \
    o1.z = (F[6] - mean) * rstd * gb.z + bb.z; \
    o1.w = (F[7] - mean) * rstd * gb.w + bb.w; \
    *(float4*)(orow + d0) = o0; \
    *(float4*)(orow + d0 + 4) = o1; } while (0)

  LN2_STORE(f0, t * 8);
  if (has2) LN2_STORE(f1, (256 + t) * 8);
#undef LN2_STORE
}

// ===============================================================
// 128^2 pipelined MFMA core (round-11, proven) for dt / Wout.
// ===============================================================
#define GEMM_PIPE_LOOP(STAGEM) \
  STAGEM(0, 0); \
  STAGEM(1, 32); \
  { \
    int nt = K / 32; \
    for (int tt = 0; tt < nt; ++tt) { \
      if (tt == nt - 1) { asm volatile("s_waitcnt vmcnt(0)" ::: "memory"); } \
      else              { asm volatile("s_waitcnt vmcnt(4)" ::: "memory"); } \
      __builtin_amdgcn_sched_barrier(0); \
      __builtin_amdgcn_s_barrier(); \
      __builtin_amdgcn_sched_barrier(0); \
      int buf = tt & 1; \
      bf16x8 a[4], b[4]; \
      _Pragma("unroll") \
      for (int i = 0; i < 4; ++i) a[i] = *(const bf16x8*)(rA + buf * 4096 + i * 16 * 32); \
      _Pragma("unroll") \
      for (int j = 0; j < 4; ++j) b[j] = *(const bf16x8*)(rB + buf * 4096 + j * 16 * 32); \
      __builtin_amdgcn_s_setprio(1); \
      _Pragma("unroll") \
      for (int i = 0; i < 4; ++i) \
        _Pragma("unroll") \
        for (int j = 0; j < 4; ++j) \
          acc[i][j] = __builtin_amdgcn_mfma_f32_16x16x32_bf16(a[i], b[j], acc[i][j], 0, 0, 0); \
      __builtin_amdgcn_s_setprio(0); \
      __builtin_amdgcn_sched_barrier(0); \
      __builtin_amdgcn_s_barrier(); \
      __builtin_amdgcn_sched_barrier(0); \
      if (tt + 2 < nt) { int k2 = (tt + 2) * 32; STAGEM(buf, k2); } \
    } \
  }

template<int EPI, bool REMAP>
__global__ __launch_bounds__(256) void gemm_mfma(
    const u16* __restrict__ A, int lda,
    const u16* __restrict__ Wb,
    const float* __restrict__ bias,
    u16* __restrict__ C1, int ldc,
    int K) {
  __shared__ u16 As[2 * 128 * 32];
  __shared__ u16 Bs[2 * 128 * 32];
  int t = threadIdx.x;
  int w = t >> 6, l = t & 63;
  int wr = w >> 1, wc = w & 1;
  int m0 = blockIdx.y * 128;
  int n0 = blockIdx.x * 128;

  f32x4 acc[4][4];
  #pragma unroll
  for (int i = 0; i < 4; ++i)
    #pragma unroll
    for (int j = 0; j < 4; ++j)
      acc[i][j] = (f32x4){0.f, 0.f, 0.f, 0.f};

  int srow = 32 * w + (l >> 2);
  int scol = (l & 3) * 8;
  const u16* gA = A  + (size_t)(m0 + srow) * lda + scol;
  const u16* gB = Wb + (size_t)(n0 + srow) * K   + scol;
  int ldsOff = (32 * w) * 32;

  int fr = l & 15;
  int kc = (l >> 4) * 8;
  const u16* rA = As + (size_t)(wr * 64 + fr) * 32 + kc;
  const u16* rB = Bs + (size_t)(wc * 64 + fr) * 32 + kc;

#define STAGE_S(buf, k0) do { \
    gload16(gA + (k0), As + (buf) * 4096 + ldsOff); \
    gload16(gA + (size_t)16 * lda + (k0), As + (buf) * 4096 + ldsOff + 16 * 32); \
    gload16(gB + (k0), Bs + (buf) * 4096 + ldsOff); \
    gload16(gB + (size_t)16 * K + (k0), Bs + (buf) * 4096 + ldsOff + 16 * 32); } while (0)

  GEMM_PIPE_LOOP(STAGE_S)
#undef STAGE_S

  int crow = (l >> 4) * 4;
  int ccol = l & 15;
  #pragma unroll
  for (int j = 0; j < 4; ++j) {
    int col = n0 + wc * 64 + j * 16 + ccol;
    int colr = col;
    if (REMAP) {
      int h = col / 192, r3 = col % 192;
      colr = (r3 / 64) * 2560 + h * 64 + (r3 & 63);
    }
    float bv = (EPI == 2) ? bias[col] : 0.f;
    #pragma unroll
    for (int i = 0; i < 4; ++i) {
      #pragma unroll
      for (int q = 0; q < 4; ++q) {
        int row = m0 + wr * 64 + i * 16 + crow + q;
        float v = acc[i][j][q];
        if constexpr (EPI == 2) v = 1.f / (1.f + expf(v + bv));
        C1[(size_t)row * ldc + colr] = f2bf(v);
      }
    }
  }
}

// ===============================================================
// 256^2 8-phase MFMA GEMM (T2 swizzle + T3/T4 counted vmcnt + T5).
// (round-12 version, unchanged)
// ===============================================================
template<int MODE>
__global__ __launch_bounds__(512) void gemm256(
    const u16* __restrict__ A,
    const u16* __restrict__ W0, const u16* __restrict__ W1,
    const u16* __restrict__ W2, const u16* __restrict__ W3,
    u16* __restrict__ C0, u16* __restrict__ C1b,
    u16* __restrict__ C2, u16* __restrict__ C3) {
  const int K = 2560;
  __shared__ u16 As[32768];   // [2 buf][2 ks][256][32]
  __shared__ u16 Bs[32768];
  int tid = threadIdx.x;
  int wid = tid >> 6, l = tid & 63;
  int wr = wid >> 2, wc = wid & 3;
  int m0 = blockIdx.y * 256;
  int n0g = blockIdx.x * 256;
  int which = (MODE == 1) ? (n0g / 2560) : 0;
  int n0 = (MODE == 1) ? (n0g - which * 2560) : n0g;
  const u16* Wsel = (MODE == 0) ? W0 :
                    ((which == 0) ? W0 : (which == 1) ? W1 : (which == 2) ? W2 : W3);
  u16* Csel = (MODE == 0) ? C0 :
              ((which == 0) ? C0 : (which == 1) ? C1b : (which == 2) ? C2 : C3);

  f32x4 acc[8][4];
  #pragma unroll
  for (int i = 0; i < 8; ++i)
    #pragma unroll
    for (int j = 0; j < 4; ++j)
      acc[i][j] = (f32x4){0.f, 0.f, 0.f, 0.f};

  int swzc = (((tid & 3) ^ ((tid >> 3) & 3)) * 8);
  const u16* sA = A    + (size_t)(m0 + (tid >> 2)) * K + swzc;
  const u16* sB = Wsel + (size_t)(n0 + (tid >> 2)) * K + swzc;

  int fr = l & 15, u = l >> 4;
  int rsw = ((u ^ ((fr >> 1) & 3)) * 8);
  const u16* rA0 = As + (size_t)(wr * 128 + fr) * 32 + rsw;
  const u16* rB0 = Bs + (size_t)(wc * 64 + fr) * 32 + rsw;

#define STGA(buf, ks, T) do { \
    const u16* _s = sA + (size_t)(T) * 64 + (ks) * 32; \
    u16* _d = As + (buf) * 16384 + (ks) * 8192 + tid * 8; \
    gload16(_s, _d); gload16(_s + (size_t)128 * K, _d + 4096); } while (0)
#define STGB(buf, ks, T) do { \
    const u16* _s = sB + (size_t)(T) * 64 + (ks) * 32; \
    u16* _d = Bs + (buf) * 16384 + (ks) * 8192 + tid * 8; \
    gload16(_s, _d); gload16(_s + (size_t)128 * K, _d + 4096); } while (0)
#define RDA(i, buf, ks) (*(const bf16x8*)(rA0 + (buf) * 16384 + (ks) * 8192 + (i) * 512))
#define RDB(j, buf, ks) (*(const bf16x8*)(rB0 + (buf) * 16384 + (ks) * 8192 + (j) * 512))
#define CLOSEB do { \
    __builtin_amdgcn_sched_barrier(0); \
    __builtin_amdgcn_s_barrier(); \
    __builtin_amdgcn_sched_barrier(0); } while (0)
#define VM8 asm volatile("s_waitcnt vmcnt(8)" ::: "memory")
#define VM4 asm volatile("s_waitcnt vmcnt(4)" ::: "memory")
#define VM0 asm volatile("s_waitcnt vmcnt(0)" ::: "memory")
#define MFMA16(mh) do { \
    acc[(mh)*4+0][0] = __builtin_amdgcn_mfma_f32_16x16x32_bf16(a0, b0, acc[(mh)*4+0][0], 0, 0, 0); \
    acc[(mh)*4+0][1] = __builtin_amdgcn_mfma_f32_16x16x32_bf16(a0, b1, acc[(mh)*4+0][1], 0, 0, 0); \
    acc[(mh)*4+0][2] = __builtin_amdgcn_mfma_f32_16x16x32_bf16(a0, b2, acc[(mh)*4+0][2], 0, 0, 0); \
    acc[(mh)*4+0][3] = __builtin_amdgcn_mfma_f32_16x16x32_bf16(a0, b3, acc[(mh)*4+0][3], 0, 0, 0); \
    acc[(mh)*4+1][0] = __builtin_amdgcn_mfma_f32_16x16x32_bf16(a1, b0, acc[(mh)*4+1][0], 0, 0, 0); \
    acc[(mh)*4+1][1] = __builtin_amdgcn_mfma_f32_16x16x32_bf16(a1, b1, acc[(mh)*4+1][1], 0, 0, 0); \
    acc[(mh)*4+1][2] = __builtin_amdgcn_mfma_f32_16x16x32_bf16(a1, b2, acc[(mh)*4+1][2], 0, 0, 0); \
    acc[(mh)*4+1][3] = __builtin_amdgcn_mfma_f32_16x16x32_bf16(a1, b3, acc[(mh)*4+1][3], 0, 0, 0); \
    acc[(mh)*4+2][0] = __builtin_amdgcn_mfma_f32_16x16x32_bf16(a2, b0, acc[(mh)*4+2][0], 0, 0, 0); \
    acc[(mh)*4+2][1] = __builtin_amdgcn_mfma_f32_16x16x32_bf16(a2, b1, acc[(mh)*4+2][1], 0, 0, 0); \
    acc[(mh)*4+2][2] = __builtin_amdgcn_mfma_f32_16x16x32_bf16(a2, b2, acc[(mh)*4+2][2], 0, 0, 0); \
    acc[(mh)*4+2][3] = __builtin_amdgcn_mfma_f32_16x16x32_bf16(a2, b3, acc[(mh)*4+2][3], 0, 0, 0); \
    acc[(mh)*4+3][0] = __builtin_amdgcn_mfma_f32_16x16x32_bf16(a3, b0, acc[(mh)*4+3][0], 0, 0, 0); \
    acc[(mh)*4+3][1] = __builtin_amdgcn_mfma_f32_16x16x32_bf16(a3, b1, acc[(mh)*4+3][1], 0, 0, 0); \
    acc[(mh)*4+3][2] = __builtin_amdgcn_mfma_f32_16x16x32_bf16(a3, b2, acc[(mh)*4+3][2], 0, 0, 0); \
    acc[(mh)*4+3][3] = __builtin_amdgcn_mfma_f32_16x16x32_bf16(a3, b3, acc[(mh)*4+3][3], 0, 0, 0); } while (0)
#define PHASE(buf, ks, mh, RB, STG_STMT) do { \
    if (RB) { b0 = RDB(0, buf, ks); b1 = RDB(1, buf, ks); \
              b2 = RDB(2, buf, ks); b3 = RDB(3, buf, ks); } \
    a0 = RDA((mh)*4+0, buf, ks); a1 = RDA((mh)*4+1, buf, ks); \
    a2 = RDA((mh)*4+2, buf, ks); a3 = RDA((mh)*4+3, buf, ks); \
    STG_STMT; \
    __builtin_amdgcn_sched_barrier(0); \
    __builtin_amdgcn_s_barrier(); \
    __builtin_amdgcn_sched_barrier(0); \
    __builtin_amdgcn_s_setprio(1); \
    MFMA16(mh); \
    __builtin_amdgcn_s_setprio(0); } while (0)

  bf16x8 a0, a1, a2, a3, b0, b1, b2, b3;

  STGA(0, 0, 0); STGB(0, 0, 0);
  STGA(0, 1, 0); STGB(0, 1, 0);
  STGA(1, 0, 1); STGB(1, 0, 1);
  VM8; CLOSEB;

  const int nIter = 20;   // K/128
  for (int it = 0; it < nIter - 1; ++it) {
    int T1 = 2 * it + 1, T2 = 2 * it + 2, T3 = 2 * it + 3;
    PHASE(0, 0, 0, 1, STGA(1, 1, T1));            CLOSEB;   // p1
    PHASE(0, 0, 1, 0, STGB(1, 1, T1));  VM8;      CLOSEB;   // p2
    PHASE(0, 1, 0, 1, STGA(0, 0, T2));            CLOSEB;   // p3
    PHASE(0, 1, 1, 0, STGB(0, 0, T2));  VM8;      CLOSEB;   // p4
    PHASE(1, 0, 0, 1, STGA(0, 1, T2));            CLOSEB;   // p5
    PHASE(1, 0, 1, 0, STGB(0, 1, T2));  VM8;      CLOSEB;   // p6
    PHASE(1, 1, 0, 1, STGA(1, 0, T3));            CLOSEB;   // p7
    PHASE(1, 1, 1, 0, STGB(1, 0, T3));  VM8;      CLOSEB;   // p8
  }
  {
    int T1 = 2 * (nIter - 1) + 1;                 // = 39
    PHASE(0, 0, 0, 1, STGA(1, 1, T1));            CLOSEB;   // p1
    PHASE(0, 0, 1, 0, STGB(1, 1, T1));  VM8;      CLOSEB;   // p2
    PHASE(0, 1, 0, 1, (void)0);                   CLOSEB;   // p3
    PHASE(0, 1, 1, 0, (void)0);         VM4;      CLOSEB;   // p4
    PHASE(1, 0, 0, 1, (void)0);                   CLOSEB;   // p5
    PHASE(1, 0, 1, 0, (void)0);         VM0;      CLOSEB;   // p6
    PHASE(1, 1, 0, 1, (void)0);                   CLOSEB;   // p7
    PHASE(1, 1, 1, 0, (void)0);                   CLOSEB;   // p8
  }
#undef STGA
#undef STGB
#undef RDA
#undef RDB
#undef CLOSEB
#undef VM8
#undef VM4
#undef VM0
#undef MFMA16
#undef PHASE

  bool sig = (MODE == 1) && (which < 2);
  int ldc = (MODE == 0) ? NPROJ : DIM;
  #pragma unroll
  for (int j = 0; j < 4; ++j) {
    int col = n0 + wc * 64 + j * 16 + fr;
    int colr = col;
    if (MODE == 0) {
      int h = col / 192, r3 = col % 192;
      colr = (r3 / 64) * 2560 + h * 64 + (r3 & 63);
    }
    #pragma unroll
    for (int i = 0; i < 8; ++i) {
      #pragma unroll
      for (int q = 0; q < 4; ++q) {
        int row = m0 + wr * 128 + i * 16 + u * 4 + q;
        float v = acc[i][j][q];
        if (sig) v = 1.f / (1.f + expf(-v));
        Csel[(size_t)row * ldc + colr] = f2bf(v);
      }
    }
  }
}

// ===============================================================
// Chunked parallel scan (round-10 structure, unchanged).
// ===============================================================
__global__ __launch_bounds__(128) void scan_local_kernel(
    const u16* __restrict__ wdec, const u16* __restrict__ proj,
    const u16* __restrict__ kb, const u16* __restrict__ vb,
    u16* __restrict__ yout,
    float* __restrict__ Sbuf, float* __restrict__ Pbuf) {
  int bx = blockIdx.x;
  int bh = bx / NC, c = bx % NC;
  int b = bh / NH, h = bh % NH;
  int wv = threadIdx.x >> 6;
  int lane = threadIdx.x & 63;
  int sg = lane >> 3, dd = lane & 7;
  int s0 = sg * 8;
  int d0 = wv * 32 + dd * 4;
  int l0 = c * CH;

  const u16* fw = wdec + ((size_t)(b * LL + l0)) * DIM + h * 64 + s0;
  const u16* fB = proj + ((size_t)(b * LL + l0)) * NPROJ + 2560 + h * 64 + s0;
  const u16* fC = fB + 2560;
  const u16* fk = kb + ((size_t)(b * LL + l0)) * DIM + h * 64 + d0;
  const u16* fv = vb + ((size_t)(b * LL + l0)) * DIM + h * 64 + d0;
  u16* py = yout + ((size_t)(b * LL + l0)) * NPROJ + h * 64 + d0;

  float st[8][4];
  float pc[8];
  #pragma unroll
  for (int i = 0; i < 8; ++i) {
    pc[i] = 1.f;
    #pragma unroll
    for (int j = 0; j < 4; ++j) st[i][j] = 0.f;
  }

#define P1_DECL(n) uint4 wS##n, BS##n, CS##n; uint2 kS##n, vS##n
#define P1_LOAD(n) do { \
    wS##n = *(const uint4*)fw; BS##n = *(const uint4*)fB; \
    CS##n = *(const uint4*)fC; kS##n = *(const uint2*)fk; \
    vS##n = *(const uint2*)fv; \
    fw += DIM; fB += NPROJ; fC += NPROJ; fk += DIM; fv += DIM; } while (0)
#define P1_PROC(n) do { \
    float wv8[8], Bv[8], Cv[8], kv4[4], pr[4]; \
    wv8[0]=bflo(wS##n.x); wv8[1]=bfhi(wS##n.x); wv8[2]=bflo(wS##n.y); wv8[3]=bfhi(wS##n.y); \
    wv8[4]=bflo(wS##n.z); wv8[5]=bfhi(wS##n.z); wv8[6]=bflo(wS##n.w); wv8[7]=bfhi(wS##n.w); \
    Bv[0]=bflo(BS##n.x); Bv[1]=bfhi(BS##n.x); Bv[2]=bflo(BS##n.y); Bv[3]=bfhi(BS##n.y); \
    Bv[4]=bflo(BS##n.z); Bv[5]=bfhi(BS##n.z); Bv[6]=bflo(BS##n.w); Bv[7]=bfhi(BS##n.w); \
    Cv[0]=bflo(CS##n.x); Cv[1]=bfhi(CS##n.x); Cv[2]=bflo(CS##n.y); Cv[3]=bfhi(CS##n.y); \
    Cv[4]=bflo(CS##n.z); Cv[5]=bfhi(CS##n.z); Cv[6]=bflo(CS##n.w); Cv[7]=bfhi(CS##n.w); \
    kv4[0]=bflo(kS##n.x)*bflo(vS##n.x); kv4[1]=bfhi(kS##n.x)*bfhi(vS##n.x); \
    kv4[2]=bflo(kS##n.y)*bflo(vS##n.y); kv4[3]=bfhi(kS##n.y)*bfhi(vS##n.y); \
    pr[0]=0.f; pr[1]=0.f; pr[2]=0.f; pr[3]=0.f; \
    _Pragma("unroll") \
    for (int i = 0; i < 8; ++i) { \
      pc[i] *= wv8[i]; \
      _Pragma("unroll") \
      for (int j = 0; j < 4; ++j) { \
        st[i][j] = fmaf(wv8[i], st[i][j], Bv[i] * kv4[j]); \
        pr[j] = fmaf(st[i][j], Cv[i], pr[j]); } } \
    _Pragma("unroll") \
    for (int j = 0; j < 4; ++j) { \
      pr[j] += __shfl_xor(pr[j], 8, 64); \
      pr[j] += __shfl_xor(pr[j], 16, 64); \
      pr[j] += __shfl_xor(pr[j], 32, 64); } \
    if (lane < 8) { \
      uint2 ov; \
      ov.x = (unsigned)f2bf(pr[0]) | ((unsigned)f2bf(pr[1]) << 16); \
      ov.y = (unsigned)f2bf(pr[2]) | ((unsigned)f2bf(pr[3]) << 16); \
      *(uint2*)py = ov; } \
    py += NPROJ; } while (0)

  P1_DECL(0); P1_DECL(1); P1_DECL(2); P1_DECL(3);
  P1_LOAD(0); P1_LOAD(1); P1_LOAD(2); P1_LOAD(3);
  for (int l = 0; l < CH; l += 4) {
    P1_PROC(0); P1_LOAD(0);
    P1_PROC(1); P1_LOAD(1);
    P1_PROC(2); P1_LOAD(2);
    P1_PROC(3); P1_LOAD(3);
  }
#undef P1_DECL
#undef P1_LOAD
#undef P1_PROC

  float* Sp = Sbuf + (((size_t)c * BH + bh) * 64 + s0) * 64 + d0;
  #pragma unroll
  for (int i = 0; i < 8; ++i) {
    float4 v; v.x = st[i][0]; v.y = st[i][1]; v.z = st[i][2]; v.w = st[i][3];
    *(float4*)(Sp + (size_t)i * 64) = v;
  }
  if (wv == 0 && dd == 0) {
    #pragma unroll
    for (int i = 0; i < 8; ++i)
      Pbuf[((size_t)c * BH + bh) * 64 + s0 + i] = pc[i];
  }
}

// ---------------------------------------------------------------
__global__ __launch_bounds__(256) void scan_combine_kernel(
    float* __restrict__ Sbuf, const float* __restrict__ Pbuf,
    float* __restrict__ fstate) {
  int bh = blockIdx.x;
  int t = threadIdx.x;
  int s = t >> 2, j0 = (t & 3) * 16;
  float stin[16];
  #pragma unroll
  for (int k = 0; k < 16; ++k) stin[k] = 0.f;
  for (int c = 0; c < NC; ++c) {
    float* Sp = Sbuf + (((size_t)c * BH + bh) * 64 + s) * 64 + j0;
    float Pc = Pbuf[((size_t)c * BH + bh) * 64 + s];
    #pragma unroll
    for (int q = 0; q < 4; ++q) {
      float4 a = *(const float4*)(Sp + q * 4);
      float4 cur;
      cur.x = stin[q*4+0]; cur.y = stin[q*4+1];
      cur.z = stin[q*4+2]; cur.w = stin[q*4+3];
      *(float4*)(Sp + q * 4) = cur;           // S slot now holds st_in for chunk c
      stin[q*4+0] = a.x + Pc * stin[q*4+0];
      stin[q*4+1] = a.y + Pc * stin[q*4+1];
      stin[q*4+2] = a.z + Pc * stin[q*4+2];
      stin[q*4+3] = a.w + Pc * stin[q*4+3];
    }
  }
  float* fp = fstate + ((size_t)bh * 64 + s) * 64 + j0;
  #pragma unroll
  for (int q = 0; q < 4; ++q) {
    float4 v;
    v.x = stin[q*4+0]; v.y = stin[q*4+1];
    v.z = stin[q*4+2]; v.w = stin[q*4+3];
    *(float4*)(fp + q * 4) = v;
  }
}

// ---------------------------------------------------------------
// Phase 3 + fused gate: y_final = r * (y_local + C.(cumw*st_in)) * g
// ---------------------------------------------------------------
__global__ __launch_bounds__(128) void scan_correct_kernel(
    const u16* __restrict__ wdec, const u16* __restrict__ proj,
    const u16* __restrict__ rb, const u16* __restrict__ gb,
    const float* __restrict__ Sbuf, u16* __restrict__ yio) {
  int bx = blockIdx.x;
  int bh = bx / NC, c = bx % NC;
  int b = bh / NH, h = bh % NH;
  int wv = threadIdx.x >> 6;
  int lane = threadIdx.x & 63;
  int sg = lane >> 3, dd = lane & 7;
  int s0 = sg * 8;
  int d0 = wv * 32 + dd * 4;
  int l0 = c * CH;

  const float* Sp = Sbuf + (((size_t)c * BH + bh) * 64 + s0) * 64 + d0;
  float stin[8][4];
  #pragma unroll
  for (int i = 0; i < 8; ++i) {
    float4 v = *(const float4*)(Sp + (size_t)i * 64);
    stin[i][0] = v.x; stin[i][1] = v.y; stin[i][2] = v.z; stin[i][3] = v.w;
  }

  const u16* fw = wdec + ((size_t)(b * LL + l0)) * DIM + h * 64 + s0;
  const u16* fC = proj + ((size_t)(b * LL + l0)) * NPROJ + 5120 + h * 64 + s0;
  const u16* fy = yio  + ((size_t)(b * LL + l0)) * NPROJ + h * 64 + d0;
  const u16* fr2 = rb + ((size_t)(b * LL + l0)) * DIM + h * 64 + d0;
  const u16* fg2 = gb + ((size_t)(b * LL + l0)) * DIM + h * 64 + d0;
  u16* py = yio + ((size_t)(b * LL + l0)) * NPROJ + h * 64 + d0;

  float pc[8];
  #pragma unroll
  for (int i = 0; i < 8; ++i) pc[i] = 1.f;

#define P3_DECL(n) uint4 wT##n, CT##n; uint2 yT##n, rT##n, gT##n
#define P3_LOAD(n) do { \
    wT##n = *(const uint4*)fw; CT##n = *(const uint4*)fC; \
    yT##n = *(const uint2*)fy; rT##n = *(const uint2*)fr2; gT##n = *(const uint2*)fg2; \
    fw += DIM; fC += NPROJ; fy += NPROJ; fr2 += DIM; fg2 += DIM; } while (0)
#define P3_PROC(n) do { \
    float wv8[8], Cv[8], ac[8], pr[4]; \
    wv8[0]=bflo(wT##n.x); wv8[1]=bfhi(wT##n.x); wv8[2]=bflo(wT##n.y); wv8[3]=bfhi(wT##n.y); \
    wv8[4]=bflo(wT##n.z); wv8[5]=bfhi(wT##n.z); wv8[6]=bflo(wT##n.w); wv8[7]=bfhi(wT##n.w); \
    Cv[0]=bflo(CT##n.x); Cv[1]=bfhi(CT##n.x); Cv[2]=bflo(CT##n.y); Cv[3]=bfhi(CT##n.y); \
    Cv[4]=bflo(CT##n.z); Cv[5]=bfhi(CT##n.z); Cv[6]=bflo(CT##n.w); Cv[7]=bfhi(CT##n.w); \
    pr[0]=0.f; pr[1]=0.f; pr[2]=0.f; pr[3]=0.f; \
    _Pragma("unroll") \
    for (int i = 0; i < 8; ++i) { \
      pc[i] *= wv8[i]; ac[i] = pc[i] * Cv[i]; \
      _Pragma("unroll") \
      for (int j = 0; j < 4; ++j) pr[j] = fmaf(ac[i], stin[i][j], pr[j]); } \
    _Pragma("unroll") \
    for (int j = 0; j < 4; ++j) { \
      pr[j] += __shfl_xor(pr[j], 8, 64); \
      pr[j] += __shfl_xor(pr[j], 16, 64); \
      pr[j] += __shfl_xor(pr[j], 32, 64); } \
    if (lane < 8) { \
      float y0 = (bflo(yT##n.x) + pr[0]) * bflo(rT##n.x) * bflo(gT##n.x); \
      float y1 = (bfhi(yT##n.x) + pr[1]) * bfhi(rT##n.x) * bfhi(gT##n.x); \
      float y2 = (bflo(yT##n.y) + pr[2]) * bflo(rT##n.y) * bflo(gT##n.y); \
      float y3 = (bfhi(yT##n.y) + pr[3]) * bfhi(rT##n.y) * bfhi(gT##n.y); \
      uint2 ov; \
      ov.x = (unsigned)f2bf(y0) | ((unsigned)f2bf(y1) << 16); \
      ov.y = (unsigned)f2bf(y2) | ((unsigned)f2bf(y3) << 16); \
      *(uint2*)py = ov; } \
    py += NPROJ; } while (0)

  P3_DECL(0); P3_DECL(1); P3_DECL(2); P3_DECL(3);
  P3_LOAD(0); P3_LOAD(1); P3_LOAD(2); P3_LOAD(3);
  for (int l = 0; l < CH; l += 4) {
    P3_PROC(0); P3_LOAD(0);
    P3_PROC(1); P3_LOAD(1);
    P3_PROC(2); P3_LOAD(2);
    P3_PROC(3); P3_LOAD(3);
  }
#undef P3_DECL
#undef P3_LOAD
#undef P3_PROC
}

// ---------------------------------------------------------------
extern "C" void kernel_launch(void* const* d_in, const int* in_sizes, int n_in,
                              void* d_out, int out_size, void* d_ws, size_t ws_size,
                              hipStream_t stream) {
  const float* x    = (const float*)d_in[0];
  const float* W_r  = (const float*)d_in[1];
  const float* W_k  = (const float*)d_in[2];
  const float* W_v  = (const float*)d_in[3];
  const float* W_g  = (const float*)d_in[4];
  const float* W_xp = (const float*)d_in[5];
  const float* W_dt = (const float*)d_in[6];
  const float* b_dt = (const float*)d_in[7];
  const float* cw   = (const float*)d_in[8];
  const float* ln1g = (const float*)d_in[9];
  const float* ln1b = (const float*)d_in[10];
  const float* ln2g = (const float*)d_in[11];
  const float* ln2b = (const float*)d_in[12];
  const float* W_o  = (const float*)d_in[13];

  float* out    = (float*)d_out;
  float* fstate = out + (size_t)MTOT * DIM;

  const size_t nBL = (size_t)MTOT * DIM;
  const size_t nPJ = (size_t)MTOT * NPROJ;
  const size_t nWX = (size_t)NPROJ * DIM;
  const size_t nDD = (size_t)DIM * DIM;
  const size_t needed = (nBL * 5 + nPJ + nWX) * sizeof(u16);  // ~207 MB
  if (ws_size < needed) {
    fill_kernel<<<(out_size + 255) / 256, 256, 0, stream>>>(out, out_size, 1234.5f);
    return;
  }

  u16* wsp  = (u16*)d_ws;
  u16* x1   = wsp;
  u16* proj = x1 + nBL;
  u16* wdec = proj + nPJ;       // reused for y2 after recurrence
  u16* rb   = wdec + nBL;
  u16* gb   = rb + nBL;
  u16* kvb  = gb + nBL;         // holds k
  u16* wscr = kvb + nBL;        // weight scratch (nWX elems); scan S/P live here
  float* Sbuf = (float*)wscr;                       // NC*BH*64*64 fp32 = 21 MB
  float* Pbuf = Sbuf + (size_t)NC * BH * 64 * 64;   // NC*BH*64 fp32 = 0.3 MB

  // v output and Wv(bf16) live in d_out's `out` region (dead until ln2;
  // fstate region untouched: 5.24M+3.28M < 10.49M floats)
  u16* vscr = (u16*)d_out;        // nBL u16 = 21 MB
  u16* wvb  = vscr + nBL;         // nDD u16 = 13.1 MB

  const int nDD4 = (int)(nDD / 4);

  // 1. conv + LN1 -> x1 (bf16)  [vectorized]
  conv_ln1_kernel<<<MTOT, 256, 0, stream>>>(x, cw, ln1g, ln1b, x1);

  // 2. proj = x1 @ W_xproj^T  (REMAP columns to [dt|B|C]) -- 256^2 8-phase
  cvt_kernel<<<2048, 256, 0, stream>>>(W_xp, wscr, NPROJ * DIM / 4);
  gemm256<0><<<dim3(NPROJ/256, MTOT/256), 512, 0, stream>>>(
      x1, wscr, nullptr, nullptr, nullptr, proj, nullptr, nullptr, nullptr);

  // 3. w = exp(-softplus(proj_dt @ W_dt^T + b_dt)) -- 128^2 core
  cvt_kernel<<<2048, 256, 0, stream>>>(W_dt, wscr, nDD4);
  gemm_mfma<2,false><<<dim3(DIM/128, MTOT/128), 256, 0, stream>>>(proj, NPROJ, wscr, b_dt, wdec, DIM, DIM);

  // 4. batched r|g|k|v GEMM -- 256^2 8-phase (N=10240, 640 blocks)
  Cvt4Args ca;
  ca.s0 = W_r; ca.s1 = W_g; ca.s2 = W_k; ca.s3 = W_v;
  ca.d0 = wscr; ca.d1 = wscr + nDD; ca.d2 = wscr + 2 * nDD; ca.d3 = wvb;
  cvt4_kernel<<<2048, 256, 0, stream>>>(ca, nDD4);
  gemm256<1><<<dim3(4 * DIM / 256, MTOT / 256), 512, 0, stream>>>(
      x1, wscr, wscr + nDD, wscr + 2 * nDD, wvb, rb, gb, kvb, vscr);

  // 5. chunked scan: local (kv=k*v inline) -> combine(fstate) -> correct(+gate)
  scan_local_kernel<<<BH * NC, 128, 0, stream>>>(wdec, proj, kvb, vscr, proj, Sbuf, Pbuf);
  scan_combine_kernel<<<BH, 256, 0, stream>>>(Sbuf, Pbuf, fstate);
  scan_correct_kernel<<<BH * NC, 128, 0, stream>>>(wdec, proj, rb, gb, Sbuf, proj);

  // 6. y2 = out_inner @ W_out^T -> wdec (reuse); A = proj y-region (lda=NPROJ)
  cvt_kernel<<<2048, 256, 0, stream>>>(W_o, wscr, nDD4);
  gemm_mfma<0,false><<<dim3(DIM/128, MTOT/128), 256, 0, stream>>>(proj, NPROJ, wscr, nullptr, wdec, DIM, DIM);

  // 7. out = LN(x1 + y2) -> fp32  [vectorized]
  ln2_kernel<<<MTOT, 256, 0, stream>>>(x1, wdec, ln2g, ln2b, out);
}